// Round 14
// baseline (232.106 us; speedup 1.0000x reference)
//
#include <hip/hip_runtime.h>
#include <cstddef>
#include <cstdint>

#define IN_F 512
#define OUT_F 128
#define NREL 10
#define MAXBINS 16000

typedef __attribute__((ext_vector_type(8))) short short8;
typedef __attribute__((ext_vector_type(4))) float f32x4;
typedef float f32x2 __attribute__((ext_vector_type(2)));

static const int kNSrc[NREL]   = {8000,16000,8000,16000,8000,4000,8000,4000,16000,4000};
static const int kNDst[NREL]   = {8000,16000,16000,8000,4000,8000,4000,8000,4000,16000};
static const int kNEdges[NREL] = {200000,800000,400000,400000,100000,100000,100000,100000,150000,150000};
static const int kRelSrcType[NREL] = {0,1,0,1,0,2,0,3,1,2};
static const int kNNodes[4] = {8000,16000,4000,4000};
static const size_t kOutOff[4] = {0, 8000ull*OUT_F, 24000ull*OUT_F, 28000ull*OUT_F};
static const size_t kHbOff[4] = {0, 8000ull*IN_F, 24000ull*IN_F, 28000ull*IN_F};
static const int kDstRels[4][4] = {{0,3,5,7},{1,2,9,-1},{4,8,-1,-1},{6,-1,-1,-1}};
static const int kNDstRels[4] = {4,3,2,1};
static const int kNblk8[NREL] = {25,98,49,49,13,13,13,13,19,19};   // ceil(E/8192), sum 311
// padded csr capacity per rel: E + 16*n_dst
static const int kCsrCap[NREL] = {328000,1056000,656000,528000,164000,228000,164000,228000,214000,406000};

// count chunks (8192): jobs 0..9 = src, 10..19 = dst
__device__ const int kCntCum[21] = {0,25,123,172,221,234,247,260,273,292,311,
                                    336,434,483,532,545,558,571,584,603,622};
#define N_CNT_CH 622
// cvt chunks (2048 vec8): per-type cum {0,250,750,875,1000} — exact fit
__device__ const int kCvtCum[5] = {0,250,750,875,1000};
#define N_CVT_CH 1000
#define N_WT_CH  80
#define PREP_BLOCKS (N_CNT_CH + N_CVT_CH + N_WT_CH)   // 1702
// place chunks (8192)
__device__ const int kPlcCum[11] = {0,25,123,172,221,234,247,260,273,292,311};
#define N_PLC_CH 311

__device__ __forceinline__ unsigned short f2bf(float f) {
  union { float f; unsigned u; } v; v.f = f;
  unsigned r = v.u + 0x7fffu + ((v.u >> 16) & 1u);
  return (unsigned short)(r >> 16);
}
// unpack uint4 (8 bf16) -> 4 f32 pairs, accumulate
__device__ __forceinline__ void acc8(f32x2* a, uint4 u) {
  union { unsigned v; float f; } lo0, hi0, lo1, hi1, lo2, hi2, lo3, hi3;
  lo0.v = u.x << 16; hi0.v = u.x & 0xffff0000u;
  lo1.v = u.y << 16; hi1.v = u.y & 0xffff0000u;
  lo2.v = u.z << 16; hi2.v = u.z & 0xffff0000u;
  lo3.v = u.w << 16; hi3.v = u.w & 0xffff0000u;
  a[0] += (f32x2){lo0.f, hi0.f};
  a[1] += (f32x2){lo1.f, hi1.f};
  a[2] += (f32x2){lo2.f, hi2.f};
  a[3] += (f32x2){lo3.f, hi3.f};
}
// async global->LDS, 16B/lane (m97 pattern)
__device__ __forceinline__ void gl_lds16(const unsigned short* g, unsigned short* l) {
  __builtin_amdgcn_global_load_lds(
      (const __attribute__((address_space(1))) unsigned int*)(g),
      (__attribute__((address_space(3))) unsigned int*)(l), 16, 0, 0);
}

// ---------------- fused prep: count(0..621) | cvt(622..1621) | WT(1622..1701) --------
struct CountJob { const int* idx; unsigned short* H; int n_edges; int nbins; };
struct PrepParams {
  CountJob cj[2 * NREL];
  const float* csrc[4]; unsigned short* cdst[4];
  const float* W[NREL]; unsigned short* WT[NREL];
};

__global__ __launch_bounds__(512) void k_prep(PrepParams p) {
  __shared__ unsigned lb[MAXBINS / 2];
  const int c = blockIdx.x;
  const int t = threadIdx.x;
  if (c < N_CNT_CH) {
    int j = 0;
    while (c >= kCntCum[j + 1]) ++j;
    const CountJob J = p.cj[j];
    const int ch = c - kCntCum[j];
    const int e0 = ch * 8192;
    const int eend = (e0 + 8192 < J.n_edges) ? e0 + 8192 : J.n_edges;
    const int nw = J.nbins >> 1;
    for (int d = t; d < nw; d += 512) lb[d] = 0;
    __syncthreads();
    for (int e = e0 + t * 4; e < eend; e += 2048) {
      const int4 v = *(const int4*)(J.idx + e);
      atomicAdd(&lb[v.x >> 1], 1u << ((v.x & 1) << 4));
      atomicAdd(&lb[v.y >> 1], 1u << ((v.y & 1) << 4));
      atomicAdd(&lb[v.z >> 1], 1u << ((v.z & 1) << 4));
      atomicAdd(&lb[v.w >> 1], 1u << ((v.w & 1) << 4));
    }
    __syncthreads();
    unsigned short* Hrow = J.H + (size_t)ch * J.nbins;
    for (int d = t; d < nw; d += 512) *(unsigned*)&Hrow[d * 2] = lb[d];
  } else if (c < N_CNT_CH + N_CVT_CH) {
    const int u = c - N_CNT_CH;
    int ty = 0;
    while (u >= kCvtCum[ty + 1]) ++ty;
    const int i0 = (u - kCvtCum[ty]) * 2048;
    const float* src = p.csrc[ty];
    unsigned short* dst = p.cdst[ty];
    for (int i = i0 + t; i < i0 + 2048; i += 512) {
      const float4 v0 = *(const float4*)(src + (size_t)i * 8);
      const float4 v1 = *(const float4*)(src + (size_t)i * 8 + 4);
      uint4 o;
      o.x = (unsigned)f2bf(v0.x) | ((unsigned)f2bf(v0.y) << 16);
      o.y = (unsigned)f2bf(v0.z) | ((unsigned)f2bf(v0.w) << 16);
      o.z = (unsigned)f2bf(v1.x) | ((unsigned)f2bf(v1.y) << 16);
      o.w = (unsigned)f2bf(v1.z) | ((unsigned)f2bf(v1.w) << 16);
      *(uint4*)(dst + (size_t)i * 8) = o;
    }
  } else {
    const int u = c - N_CNT_CH - N_CVT_CH;
    const int r = u >> 3;
    const int g0 = (u & 7) * 2048;
    const float* W = p.W[r];
    unsigned short* WT = p.WT[r];
    for (int g = g0 + t; g < g0 + 2048; g += 512) {
      const int k = g >> 5;
      const int n0 = (g & 31) * 4;
      const float4 w = *(const float4*)(W + (size_t)k * OUT_F + n0);
      WT[(size_t)(n0 + 0) * IN_F + k] = f2bf(w.x);
      WT[(size_t)(n0 + 1) * IN_F + k] = f2bf(w.y);
      WT[(size_t)(n0 + 2) * IN_F + k] = f2bf(w.z);
      WT[(size_t)(n0 + 3) * IN_F + k] = f2bf(w.w);
    }
  }
}

// ---------------- fused column-sum (src) + per-bin prefix (dst) over H ---------------
struct SBJob { unsigned short* H; int* tot; int nbins; int nblocks; int prefix; };
struct SBParams { SBJob j[2 * NREL]; };

__global__ __launch_bounds__(256) void k_sumbase(SBParams p) {
  SBJob J = p.j[blockIdx.y];
  const int bin = blockIdx.x * 256 + threadIdx.x;
  if (bin >= J.nbins) return;
  int run = 0;
  if (J.prefix) {
    for (int b = 0; b < J.nblocks; ++b) {
      const size_t o = (size_t)b * J.nbins + bin;
      const int cc = J.H[o];
      J.H[o] = (unsigned short)run;
      run += cc;
    }
  } else {
    for (int b = 0; b < J.nblocks; ++b) run += J.H[(size_t)b * J.nbins + bin];
  }
  J.tot[bin] = run;
}

// ---------------- exclusive scan over PADDED counts + pad-fill with dummy ------------
struct ScanRel { const int* tot; int* rowstart; unsigned short* csr; int n; int dummy; };
struct ScanParams { ScanRel r[NREL]; };

__global__ __launch_bounds__(512) void k_scan(ScanParams p) {
  ScanRel R = p.r[blockIdx.x];
  const int t = threadIdx.x;
  const int lane = t & 63, wv = t >> 6;
  const int base = t * 32;
  int v[32];
  int s = 0;
#pragma unroll
  for (int i = 0; i < 32; ++i) {
    int e = base + i;
    int x = (e < R.n) ? R.tot[e] : 0;
    int xp = (x + 15) & ~15;          // pad segment to multiple of 16
    v[i] = s; s += xp;
  }
  int inc = s;
#pragma unroll
  for (int off = 1; off < 64; off <<= 1) {
    int u = __shfl_up(inc, off);
    if (lane >= off) inc += u;
  }
  __shared__ int wsum[8];
  if (lane == 63) wsum[wv] = inc;
  __syncthreads();
  int carry = 0, total = 0;
#pragma unroll
  for (int w = 0; w < 8; ++w) {
    int x = wsum[w];
    if (w < wv) carry += x;
    total += x;
  }
  const int tb = carry + (inc - s);
#pragma unroll
  for (int i = 0; i < 32; ++i) {
    int e = base + i;
    if (e < R.n) {
      const int x = R.tot[e];
      const int xp = (x + 15) & ~15;
      const int lo = tb + v[i];
      R.rowstart[e] = lo;
      for (int pk = x; pk < xp; ++pk) R.csr[lo + pk] = (unsigned short)R.dummy;
    }
  }
  if (t == 0) R.rowstart[R.n] = total;
}

// ---------------- place: 8192-edge chunks, LDS cursors -------------------------------
struct PlaceJob { const int* src; const int* dst; const unsigned short* Hpre; const int* rowstart;
                  unsigned short* csr; int n_edges; int nbins; };
struct PlaceParams { PlaceJob j[NREL]; };

__global__ __launch_bounds__(1024) void k_place(PlaceParams p) {
  __shared__ int lb[MAXBINS];
  const int c = blockIdx.x;
  const int t = threadIdx.x;
  int j = 0;
  while (c >= kPlcCum[j + 1]) ++j;
  const PlaceJob J = p.j[j];
  const int ch = c - kPlcCum[j];
  const int e0 = ch * 8192;
  const int eend = (e0 + 8192 < J.n_edges) ? e0 + 8192 : J.n_edges;
  const unsigned short* Hrow = J.Hpre + (size_t)ch * J.nbins;
  for (int d = t; d < J.nbins; d += 1024) lb[d] = J.rowstart[d] + (int)Hrow[d];
  __syncthreads();
  for (int e = e0 + t * 4; e < eend; e += 4096) {
    const int4 dv = *(const int4*)(J.dst + e);
    const int4 sv = *(const int4*)(J.src + e);
    const int p0 = atomicAdd(&lb[dv.x], 1); J.csr[p0] = (unsigned short)sv.x;
    const int p1 = atomicAdd(&lb[dv.y], 1); J.csr[p1] = (unsigned short)sv.y;
    const int p2 = atomicAdd(&lb[dv.z], 1); J.csr[p2] = (unsigned short)sv.z;
    const int p3 = atomicAdd(&lb[dv.w], 1); J.csr[p3] = (unsigned short)sv.w;
  }
}

// ---------------- y_r = (hb @ W_r) * deg_out^-1/2 — m97-style gload_lds MFMA ---------
// blocks >= GEMM_JOBS zero the per-relation dummy y row (gather target for pad edges).
struct GemmRel { const unsigned short* hb; const unsigned short* WT; unsigned short* y;
                 const int* deg_out; int n_src; };
struct GemmParams { GemmRel r[NREL]; };

#define GEMM_JOBS 723

__global__ __launch_bounds__(256) void k_gemm(GemmParams p) {
  if (blockIdx.x >= GEMM_JOBS) {
    const int r = blockIdx.x - GEMM_JOBS;
    if (threadIdx.x < 64)
      ((unsigned*)(p.r[r].y + (size_t)p.r[r].n_src * OUT_F))[threadIdx.x] = 0u;
    return;
  }
  // bijective XCD swizzle: orig -> jobid (m204)
  const int orig = blockIdx.x;
  const int xcd = orig & 7;
  const int i8 = orig >> 3;
  const int q = GEMM_JOBS / 8, rm = GEMM_JOBS % 8;   // 90, 3
  const int g = (xcd < rm ? xcd * (q + 1) : rm * (q + 1) + (xcd - rm) * q) + i8;
  static const int dr[4] = {0, 2, 4, 6};
  static const int pr[3] = {1, 3, 8};
  static const int xr[2] = {5, 9};
  int rel, tile;
  if (g < 252)      { rel = dr[g & 3]; tile = g >> 2; }
  else if (g < 627) { int u = g - 252; rel = pr[u % 3]; tile = u / 3; }
  else if (g < 691) { int u = g - 627; rel = xr[u & 1]; tile = u >> 1; }
  else              { rel = 7; tile = g - 691; }

  const GemmRel R = p.r[rel];
  const int m0 = tile * 128;

  __shared__ unsigned short As[128 * 64];
  __shared__ unsigned short Bs[128 * 64];

  const int t = threadIdx.x;
  const int lane = t & 63, wid = t >> 6;
  const int wm = (wid >> 1) * 64, wn = (wid & 1) * 64;
  const int l16 = lane & 15;
  const int fcol = lane >> 4;
  const int srow8 = lane >> 3;
  const int slot  = lane & 7;
  const int scol  = (slot ^ srow8) * 8;

  const unsigned short* ga[4];
  const unsigned short* gb[4];
#pragma unroll
  for (int i = 0; i < 4; ++i) {
    const int lrow = wid * 32 + i * 8 + srow8;
    int grow = m0 + lrow;
    if (grow > R.n_src - 1) grow = R.n_src - 1;
    ga[i] = R.hb + (size_t)grow * IN_F + scol;
    gb[i] = R.WT + (size_t)lrow * IN_F + scol;
  }

  f32x4 acc[4][4];
#pragma unroll
  for (int i = 0; i < 4; ++i)
#pragma unroll
    for (int j = 0; j < 4; ++j) acc[i][j] = (f32x4){0.f, 0.f, 0.f, 0.f};

#pragma unroll 1
  for (int s = 0; s < 8; ++s) {
    const int k0 = s * 64;
#pragma unroll
    for (int i = 0; i < 4; ++i) {
      gl_lds16(ga[i] + k0, &As[(wid * 32 + i * 8) * 64]);
      gl_lds16(gb[i] + k0, &Bs[(wid * 32 + i * 8) * 64]);
    }
    __syncthreads();
#pragma unroll
    for (int kk = 0; kk < 2; ++kk) {
      const int csl = ((kk * 4 + fcol) ^ (l16 & 7)) * 8;
      short8 af[4], bf[4];
#pragma unroll
      for (int f = 0; f < 4; ++f) {
        af[f] = *(const short8*)&As[(wm + f * 16 + l16) * 64 + csl];
        bf[f] = *(const short8*)&Bs[(wn + f * 16 + l16) * 64 + csl];
      }
#pragma unroll
      for (int i = 0; i < 4; ++i)
#pragma unroll
        for (int j = 0; j < 4; ++j)
          acc[i][j] = __builtin_amdgcn_mfma_f32_16x16x32_bf16(af[i], bf[j], acc[i][j], 0, 0, 0);
    }
    __syncthreads();
  }

  const int r4 = (lane >> 4) * 4;  // C/D: col=lane&15, row=(lane>>4)*4+q
#pragma unroll
  for (int i = 0; i < 4; ++i) {
#pragma unroll
    for (int qq = 0; qq < 4; ++qq) {
      const int row = m0 + wm + i * 16 + r4 + qq;
      if (row < R.n_src) {
        const int d = R.deg_out[row];
        const float sc = rsqrtf((float)(d > 1 ? d : 1));
#pragma unroll
        for (int j = 0; j < 4; ++j) {
          const int col = wn + j * 16 + l16;
          R.y[(size_t)row * OUT_F + col] = f2bf(acc[i][j][qq] * sc);
        }
      }
    }
  }
}

// ---------------- gather-aggregate + bias + relu (pad-16 segments, tail-free) --------
struct AggRel { const int* rowstart; const int* deg; const unsigned short* csr;
                const unsigned short* y; const float* b; };
struct AggType { AggRel r[4]; int n_rels; int n_nodes; float* out; };
struct AggParams { AggType t[4]; };

__global__ __launch_bounds__(256) void k_aggregate(AggParams p) {
  const AggType& T = p.t[blockIdx.y];
  const int node = blockIdx.x * 4 + (threadIdx.x >> 6);
  if (node >= T.n_nodes) return;
  const int lane = threadIdx.x & 63;
  const int quarter = lane >> 4;
  const int c8 = (lane & 15) * 8;
  f32x2 ac2[4] = {{0.f,0.f},{0.f,0.f},{0.f,0.f},{0.f,0.f}};
  float bs[8] = {0,0,0,0,0,0,0,0};
#pragma unroll
  for (int rr = 0; rr < 4; ++rr) {
    if (rr < T.n_rels) {
      const AggRel R = T.r[rr];
      const int lo = R.rowstart[node];
      const int hi = R.rowstart[node + 1];   // lo + pad16(deg)
      f32x2 rx2[4] = {{0.f,0.f},{0.f,0.f},{0.f,0.f},{0.f,0.f}};
      for (int k = lo + quarter; k < hi; k += 16) {   // tail-free: 16 rows in flight/wave
        const int s0 = R.csr[k];
        const int s1 = R.csr[k + 4];
        const int s2 = R.csr[k + 8];
        const int s3 = R.csr[k + 12];
        const uint4 u0 = *(const uint4*)(R.y + (size_t)s0 * OUT_F + c8);
        const uint4 u1 = *(const uint4*)(R.y + (size_t)s1 * OUT_F + c8);
        const uint4 u2 = *(const uint4*)(R.y + (size_t)s2 * OUT_F + c8);
        const uint4 u3 = *(const uint4*)(R.y + (size_t)s3 * OUT_F + c8);
        acc8(rx2, u0); acc8(rx2, u1); acc8(rx2, u2); acc8(rx2, u3);
      }
      const int deg = R.deg[node];
      const float s = rsqrtf((float)(deg > 1 ? deg : 1));
      const f32x2 sc2 = {s, s};
#pragma unroll
      for (int qd = 0; qd < 4; ++qd) ac2[qd] += rx2[qd] * sc2;
      const float4 b0 = *(const float4*)(R.b + c8);
      const float4 b1 = *(const float4*)(R.b + c8 + 4);
      bs[0] += b0.x; bs[1] += b0.y; bs[2] += b0.z; bs[3] += b0.w;
      bs[4] += b1.x; bs[5] += b1.y; bs[6] += b1.z; bs[7] += b1.w;
    }
  }
  float ac[8] = {ac2[0].x, ac2[0].y, ac2[1].x, ac2[1].y,
                 ac2[2].x, ac2[2].y, ac2[3].x, ac2[3].y};
#pragma unroll
  for (int qd = 0; qd < 8; ++qd) {
    ac[qd] += __shfl_xor(ac[qd], 16);
    ac[qd] += __shfl_xor(ac[qd], 32);
    ac[qd] += bs[qd];
    ac[qd] = ac[qd] > 0.f ? ac[qd] : 0.f;
  }
  if (quarter == 0) {
    float* dst = T.out + (size_t)node * OUT_F + c8;
    float4 o0 = {ac[0], ac[1], ac[2], ac[3]};
    float4 o1 = {ac[4], ac[5], ac[6], ac[7]};
    *(float4*)dst = o0;
    *(float4*)(dst + 4) = o1;
  }
}

// ---------------- host ----------------
extern "C" void kernel_launch(void* const* d_in, const int* in_sizes, int n_in,
                              void* d_out, int out_size, void* d_ws, size_t ws_size,
                              hipStream_t stream) {
  const float* h[4];
  for (int i = 0; i < 4; ++i) h[i] = (const float*)d_in[i];
  const float* W[NREL]; const float* b[NREL];
  const int* src[NREL]; const int* dst[NREL];
  for (int r = 0; r < NREL; ++r) {
    W[r]   = (const float*)d_in[4 + 2 * r];
    b[r]   = (const float*)d_in[5 + 2 * r];
    src[r] = (const int*)d_in[24 + 2 * r];
    dst[r] = (const int*)d_in[25 + 2 * r];
  }
  float* out = (float*)d_out;

  char* ws = (char*)d_ws;
  size_t off = 0;
  auto alloc = [&](size_t bytes) -> char* {
    char* p = ws + off;
    off = (off + bytes + 255) & ~(size_t)255;
    return p;
  };
  int* degO[NREL];
  { char* base = alloc((size_t)92000 * 4); size_t o = 0;
    for (int r = 0; r < NREL; ++r) { degO[r] = (int*)(base + o); o += (size_t)kNSrc[r] * 4; } }
  int* totI[NREL];
  { char* base = alloc((size_t)92000 * 4); size_t o = 0;
    for (int r = 0; r < NREL; ++r) { totI[r] = (int*)(base + o); o += (size_t)kNDst[r] * 4; } }
  int* rowst[NREL];
  { char* base = alloc((size_t)(92000 + NREL) * 4); size_t o = 0;
    for (int r = 0; r < NREL; ++r) { rowst[r] = (int*)(base + o); o += (size_t)(kNDst[r] + 1) * 4; } }
  unsigned short* csr[NREL];
  { size_t tot = 0; for (int r = 0; r < NREL; ++r) tot += (size_t)kCsrCap[r];
    char* base = alloc(tot * 2); size_t o = 0;
    for (int r = 0; r < NREL; ++r) { csr[r] = (unsigned short*)(base + o); o += (size_t)kCsrCap[r] * 2; } }
  unsigned short* WT[NREL];
  { char* base = alloc((size_t)NREL * IN_F * OUT_F * 2); size_t o = 0;
    for (int r = 0; r < NREL; ++r) { WT[r] = (unsigned short*)(base + o); o += (size_t)IN_F * OUT_F * 2; } }
  unsigned short* hb = (unsigned short*)alloc((size_t)32000 * IN_F * 2);

  // H region and y (+1 dummy row per rel) overlap: H dead after place, y written in gemm.
  size_t hBytes = 0;
  for (int r = 0; r < NREL; ++r) hBytes += (size_t)kNblk8[r] * (kNSrc[r] + kNDst[r]) * 2;
  size_t yBytes = (size_t)(92000 + NREL) * OUT_F * 2;
  char* HY = alloc(hBytes > yBytes ? hBytes : yBytes);
  unsigned short* Hsrc[NREL]; unsigned short* Hdst[NREL];
  { size_t o = 0;
    for (int r = 0; r < NREL; ++r) { Hsrc[r] = (unsigned short*)(HY + o); o += (size_t)kNblk8[r] * kNSrc[r] * 2; }
    for (int r = 0; r < NREL; ++r) { Hdst[r] = (unsigned short*)(HY + o); o += (size_t)kNblk8[r] * kNDst[r] * 2; } }
  unsigned short* y[NREL];
  { size_t o = 0;
    for (int r = 0; r < NREL; ++r) { y[r] = (unsigned short*)(HY + o); o += (size_t)(kNSrc[r] + 1) * OUT_F * 2; } }

  // 1) fused prep: count + cvt + W^T
  PrepParams pr;
  for (int r = 0; r < NREL; ++r) {
    pr.cj[r]        = CountJob{src[r], Hsrc[r], kNEdges[r], kNSrc[r]};
    pr.cj[NREL + r] = CountJob{dst[r], Hdst[r], kNEdges[r], kNDst[r]};
  }
  for (int ty = 0; ty < 4; ++ty) {
    pr.csrc[ty] = h[ty];
    pr.cdst[ty] = hb + kHbOff[ty];
  }
  for (int r = 0; r < NREL; ++r) { pr.W[r] = W[r]; pr.WT[r] = WT[r]; }
  k_prep<<<PREP_BLOCKS, 512, 0, stream>>>(pr);

  // 2) column-sum (src) + prefix (dst)
  SBParams sb;
  for (int r = 0; r < NREL; ++r) {
    sb.j[r]        = SBJob{Hsrc[r], degO[r], kNSrc[r], kNblk8[r], 0};
    sb.j[NREL + r] = SBJob{Hdst[r], totI[r], kNDst[r], kNblk8[r], 1};
  }
  k_sumbase<<<dim3((16000 + 255) / 256, 2 * NREL), 256, 0, stream>>>(sb);

  // 3) padded scan + pad-fill
  ScanParams sp;
  for (int r = 0; r < NREL; ++r) sp.r[r] = ScanRel{totI[r], rowst[r], csr[r], kNDst[r], kNSrc[r]};
  k_scan<<<NREL, 512, 0, stream>>>(sp);

  // 4) place
  PlaceParams pp;
  for (int r = 0; r < NREL; ++r)
    pp.j[r] = PlaceJob{src[r], dst[r], Hdst[r], rowst[r], csr[r], kNEdges[r], kNDst[r]};
  k_place<<<N_PLC_CH, 1024, 0, stream>>>(pp);

  // 5) GEMM (+10 dummy-row-zero blocks)
  GemmParams gp;
  for (int r = 0; r < NREL; ++r)
    gp.r[r] = GemmRel{hb + kHbOff[kRelSrcType[r]], WT[r], y[r], degO[r], kNSrc[r]};
  k_gemm<<<GEMM_JOBS + NREL, 256, 0, stream>>>(gp);

  // 6) aggregate (tail-free)
  AggParams ap;
  for (int ti = 0; ti < 4; ++ti) {
    AggType& T = ap.t[ti];
    T.n_nodes = kNNodes[ti];
    T.n_rels = kNDstRels[ti];
    T.out = out + kOutOff[ti];
    for (int j = 0; j < 4; ++j) {
      int r = kDstRels[ti][j];
      if (r < 0) r = kDstRels[ti][0];
      T.r[j] = AggRel{rowst[r], totI[r], csr[r], y[r], b[r]};
    }
  }
  k_aggregate<<<dim3((16000 + 3) / 4, 4), 256, 0, stream>>>(ap);
}

// Round 15
// 194.988 us; speedup vs baseline: 1.1904x; 1.1904x over previous
//
#include <hip/hip_runtime.h>
#include <cstddef>
#include <cstdint>

#define IN_F 512
#define OUT_F 128
#define NREL 10
#define MAXBINS 16000

typedef __attribute__((ext_vector_type(8))) short short8;
typedef __attribute__((ext_vector_type(4))) float f32x4;
typedef float f32x2 __attribute__((ext_vector_type(2)));

static const int kNSrc[NREL]   = {8000,16000,8000,16000,8000,4000,8000,4000,16000,4000};
static const int kNDst[NREL]   = {8000,16000,16000,8000,4000,8000,4000,8000,4000,16000};
static const int kNEdges[NREL] = {200000,800000,400000,400000,100000,100000,100000,100000,150000,150000};
static const int kRelSrcType[NREL] = {0,1,0,1,0,2,0,3,1,2};
static const int kNNodes[4] = {8000,16000,4000,4000};
static const size_t kOutOff[4] = {0, 8000ull*OUT_F, 24000ull*OUT_F, 28000ull*OUT_F};
static const size_t kHbOff[4] = {0, 8000ull*IN_F, 24000ull*IN_F, 28000ull*IN_F};
static const int kDstRels[4][4] = {{0,3,5,7},{1,2,9,-1},{4,8,-1,-1},{6,-1,-1,-1}};
static const int kNDstRels[4] = {4,3,2,1};
static const int kNblk8[NREL] = {25,98,49,49,13,13,13,13,19,19};   // ceil(E/8192), sum 311
// padded csr capacity per rel: E + 16*n_dst
static const int kCsrCap[NREL] = {328000,1056000,656000,528000,164000,228000,164000,228000,214000,406000};

// count chunks (8192): jobs 0..9 = src, 10..19 = dst
__device__ const int kCntCum[21] = {0,25,123,172,221,234,247,260,273,292,311,
                                    336,434,483,532,545,558,571,584,603,622};
#define N_CNT_CH 622
// cvt chunks (2048 vec8): per-type cum {0,250,750,875,1000} — exact fit
__device__ const int kCvtCum[5] = {0,250,750,875,1000};
#define N_CVT_CH 1000
#define N_WT_CH  80
#define PREP_BLOCKS (N_CNT_CH + N_CVT_CH + N_WT_CH)   // 1702
// place chunks (8192)
__device__ const int kPlcCum[11] = {0,25,123,172,221,234,247,260,273,292,311};
#define N_PLC_CH 311

__device__ __forceinline__ unsigned short f2bf(float f) {
  union { float f; unsigned u; } v; v.f = f;
  unsigned r = v.u + 0x7fffu + ((v.u >> 16) & 1u);
  return (unsigned short)(r >> 16);
}
// unpack uint4 (8 bf16) -> 4 f32 pairs, accumulate
__device__ __forceinline__ void acc8(f32x2* a, uint4 u) {
  union { unsigned v; float f; } lo0, hi0, lo1, hi1, lo2, hi2, lo3, hi3;
  lo0.v = u.x << 16; hi0.v = u.x & 0xffff0000u;
  lo1.v = u.y << 16; hi1.v = u.y & 0xffff0000u;
  lo2.v = u.z << 16; hi2.v = u.z & 0xffff0000u;
  lo3.v = u.w << 16; hi3.v = u.w & 0xffff0000u;
  a[0] += (f32x2){lo0.f, hi0.f};
  a[1] += (f32x2){lo1.f, hi1.f};
  a[2] += (f32x2){lo2.f, hi2.f};
  a[3] += (f32x2){lo3.f, hi3.f};
}
// async global->LDS, 16B/lane (m97 pattern)
__device__ __forceinline__ void gl_lds16(const unsigned short* g, unsigned short* l) {
  __builtin_amdgcn_global_load_lds(
      (const __attribute__((address_space(1))) unsigned int*)(g),
      (__attribute__((address_space(3))) unsigned int*)(l), 16, 0, 0);
}

// ---------------- fused prep: count(0..621) | cvt(622..1621) | WT(1622..1701) --------
struct CountJob { const int* idx; unsigned short* H; int n_edges; int nbins; };
struct PrepParams {
  CountJob cj[2 * NREL];
  const float* csrc[4]; unsigned short* cdst[4];
  const float* W[NREL]; unsigned short* WT[NREL];
};

__global__ __launch_bounds__(512) void k_prep(PrepParams p) {
  __shared__ unsigned lb[MAXBINS / 2];
  const int c = blockIdx.x;
  const int t = threadIdx.x;
  if (c < N_CNT_CH) {
    int j = 0;
    while (c >= kCntCum[j + 1]) ++j;
    const CountJob J = p.cj[j];
    const int ch = c - kCntCum[j];
    const int e0 = ch * 8192;
    const int eend = (e0 + 8192 < J.n_edges) ? e0 + 8192 : J.n_edges;
    const int nw = J.nbins >> 1;
    for (int d = t; d < nw; d += 512) lb[d] = 0;
    __syncthreads();
    for (int e = e0 + t * 4; e < eend; e += 2048) {
      const int4 v = *(const int4*)(J.idx + e);
      atomicAdd(&lb[v.x >> 1], 1u << ((v.x & 1) << 4));
      atomicAdd(&lb[v.y >> 1], 1u << ((v.y & 1) << 4));
      atomicAdd(&lb[v.z >> 1], 1u << ((v.z & 1) << 4));
      atomicAdd(&lb[v.w >> 1], 1u << ((v.w & 1) << 4));
    }
    __syncthreads();
    unsigned short* Hrow = J.H + (size_t)ch * J.nbins;
    for (int d = t; d < nw; d += 512) *(unsigned*)&Hrow[d * 2] = lb[d];
  } else if (c < N_CNT_CH + N_CVT_CH) {
    const int u = c - N_CNT_CH;
    int ty = 0;
    while (u >= kCvtCum[ty + 1]) ++ty;
    const int i0 = (u - kCvtCum[ty]) * 2048;
    const float* src = p.csrc[ty];
    unsigned short* dst = p.cdst[ty];
    for (int i = i0 + t; i < i0 + 2048; i += 512) {
      const float4 v0 = *(const float4*)(src + (size_t)i * 8);
      const float4 v1 = *(const float4*)(src + (size_t)i * 8 + 4);
      uint4 o;
      o.x = (unsigned)f2bf(v0.x) | ((unsigned)f2bf(v0.y) << 16);
      o.y = (unsigned)f2bf(v0.z) | ((unsigned)f2bf(v0.w) << 16);
      o.z = (unsigned)f2bf(v1.x) | ((unsigned)f2bf(v1.y) << 16);
      o.w = (unsigned)f2bf(v1.z) | ((unsigned)f2bf(v1.w) << 16);
      *(uint4*)(dst + (size_t)i * 8) = o;
    }
  } else {
    const int u = c - N_CNT_CH - N_CVT_CH;
    const int r = u >> 3;
    const int g0 = (u & 7) * 2048;
    const float* W = p.W[r];
    unsigned short* WT = p.WT[r];
    for (int g = g0 + t; g < g0 + 2048; g += 512) {
      const int k = g >> 5;
      const int n0 = (g & 31) * 4;
      const float4 w = *(const float4*)(W + (size_t)k * OUT_F + n0);
      WT[(size_t)(n0 + 0) * IN_F + k] = f2bf(w.x);
      WT[(size_t)(n0 + 1) * IN_F + k] = f2bf(w.y);
      WT[(size_t)(n0 + 2) * IN_F + k] = f2bf(w.z);
      WT[(size_t)(n0 + 3) * IN_F + k] = f2bf(w.w);
    }
  }
}

// ---------------- fused column-sum (src) + per-bin prefix (dst) over H ---------------
struct SBJob { unsigned short* H; int* tot; int nbins; int nblocks; int prefix; };
struct SBParams { SBJob j[2 * NREL]; };

__global__ __launch_bounds__(256) void k_sumbase(SBParams p) {
  SBJob J = p.j[blockIdx.y];
  const int bin = blockIdx.x * 256 + threadIdx.x;
  if (bin >= J.nbins) return;
  int run = 0;
  if (J.prefix) {
    for (int b = 0; b < J.nblocks; ++b) {
      const size_t o = (size_t)b * J.nbins + bin;
      const int cc = J.H[o];
      J.H[o] = (unsigned short)run;
      run += cc;
    }
  } else {
    for (int b = 0; b < J.nblocks; ++b) run += J.H[(size_t)b * J.nbins + bin];
  }
  J.tot[bin] = run;
}

// ---------------- exclusive scan over PADDED counts (pure scan, no fill) -------------
struct ScanRel { const int* tot; int* rowstart; int n; };
struct ScanParams { ScanRel r[NREL]; };

__global__ __launch_bounds__(512) void k_scan(ScanParams p) {
  ScanRel R = p.r[blockIdx.x];
  const int t = threadIdx.x;
  const int lane = t & 63, wv = t >> 6;
  const int base = t * 32;
  int v[32];
  int s = 0;
#pragma unroll
  for (int i = 0; i < 32; ++i) {
    int e = base + i;
    int x = (e < R.n) ? R.tot[e] : 0;
    int xp = (x + 15) & ~15;          // pad segment to multiple of 16
    v[i] = s; s += xp;
  }
  int inc = s;
#pragma unroll
  for (int off = 1; off < 64; off <<= 1) {
    int u = __shfl_up(inc, off);
    if (lane >= off) inc += u;
  }
  __shared__ int wsum[8];
  if (lane == 63) wsum[wv] = inc;
  __syncthreads();
  int carry = 0, total = 0;
#pragma unroll
  for (int w = 0; w < 8; ++w) {
    int x = wsum[w];
    if (w < wv) carry += x;
    total += x;
  }
  const int tb = carry + (inc - s);
#pragma unroll
  for (int i = 0; i < 32; ++i) {
    int e = base + i;
    if (e < R.n) R.rowstart[e] = tb + v[i];
  }
  if (t == 0) R.rowstart[R.n] = total;
}

// ---------------- pad-fill: one thread per dst node, parallel ------------------------
struct PadJob { const int* tot; const int* rowstart; unsigned short* csr; int nbins; int dummy; };
struct PadParams { PadJob j[NREL]; };

__global__ __launch_bounds__(256) void k_pad(PadParams p) {
  const PadJob J = p.j[blockIdx.y];
  const int bin = blockIdx.x * 256 + threadIdx.x;
  if (bin >= J.nbins) return;
  const int x = J.tot[bin];
  const int xp = (x + 15) & ~15;
  const int lo = J.rowstart[bin];
  const unsigned short d = (unsigned short)J.dummy;
  for (int pk = x; pk < xp; ++pk) J.csr[lo + pk] = d;
}

// ---------------- place: 8192-edge chunks, LDS cursors -------------------------------
struct PlaceJob { const int* src; const int* dst; const unsigned short* Hpre; const int* rowstart;
                  unsigned short* csr; int n_edges; int nbins; };
struct PlaceParams { PlaceJob j[NREL]; };

__global__ __launch_bounds__(1024) void k_place(PlaceParams p) {
  __shared__ int lb[MAXBINS];
  const int c = blockIdx.x;
  const int t = threadIdx.x;
  int j = 0;
  while (c >= kPlcCum[j + 1]) ++j;
  const PlaceJob J = p.j[j];
  const int ch = c - kPlcCum[j];
  const int e0 = ch * 8192;
  const int eend = (e0 + 8192 < J.n_edges) ? e0 + 8192 : J.n_edges;
  const unsigned short* Hrow = J.Hpre + (size_t)ch * J.nbins;
  for (int d = t; d < J.nbins; d += 1024) lb[d] = J.rowstart[d] + (int)Hrow[d];
  __syncthreads();
  for (int e = e0 + t * 4; e < eend; e += 4096) {
    const int4 dv = *(const int4*)(J.dst + e);
    const int4 sv = *(const int4*)(J.src + e);
    const int p0 = atomicAdd(&lb[dv.x], 1); J.csr[p0] = (unsigned short)sv.x;
    const int p1 = atomicAdd(&lb[dv.y], 1); J.csr[p1] = (unsigned short)sv.y;
    const int p2 = atomicAdd(&lb[dv.z], 1); J.csr[p2] = (unsigned short)sv.z;
    const int p3 = atomicAdd(&lb[dv.w], 1); J.csr[p3] = (unsigned short)sv.w;
  }
}

// ---------------- y_r = (hb @ W_r) * deg_out^-1/2 — m97-style gload_lds MFMA ---------
struct GemmRel { const unsigned short* hb; const unsigned short* WT; unsigned short* y;
                 const int* deg_out; int n_src; };
struct GemmParams { GemmRel r[NREL]; };

#define GEMM_JOBS 723

__global__ __launch_bounds__(256) void k_gemm(GemmParams p) {
  if (blockIdx.x >= GEMM_JOBS) {
    const int r = blockIdx.x - GEMM_JOBS;
    if (threadIdx.x < 64)
      ((unsigned*)(p.r[r].y + (size_t)p.r[r].n_src * OUT_F))[threadIdx.x] = 0u;
    return;
  }
  // bijective XCD swizzle: orig -> jobid (m204)
  const int orig = blockIdx.x;
  const int xcd = orig & 7;
  const int i8 = orig >> 3;
  const int q = GEMM_JOBS / 8, rm = GEMM_JOBS % 8;   // 90, 3
  const int g = (xcd < rm ? xcd * (q + 1) : rm * (q + 1) + (xcd - rm) * q) + i8;
  static const int dr[4] = {0, 2, 4, 6};
  static const int pr[3] = {1, 3, 8};
  static const int xr[2] = {5, 9};
  int rel, tile;
  if (g < 252)      { rel = dr[g & 3]; tile = g >> 2; }
  else if (g < 627) { int u = g - 252; rel = pr[u % 3]; tile = u / 3; }
  else if (g < 691) { int u = g - 627; rel = xr[u & 1]; tile = u >> 1; }
  else              { rel = 7; tile = g - 691; }

  const GemmRel R = p.r[rel];
  const int m0 = tile * 128;

  __shared__ unsigned short As[128 * 64];
  __shared__ unsigned short Bs[128 * 64];

  const int t = threadIdx.x;
  const int lane = t & 63, wid = t >> 6;
  const int wm = (wid >> 1) * 64, wn = (wid & 1) * 64;
  const int l16 = lane & 15;
  const int fcol = lane >> 4;
  const int srow8 = lane >> 3;
  const int slot  = lane & 7;
  const int scol  = (slot ^ srow8) * 8;

  const unsigned short* ga[4];
  const unsigned short* gb[4];
#pragma unroll
  for (int i = 0; i < 4; ++i) {
    const int lrow = wid * 32 + i * 8 + srow8;
    int grow = m0 + lrow;
    if (grow > R.n_src - 1) grow = R.n_src - 1;
    ga[i] = R.hb + (size_t)grow * IN_F + scol;
    gb[i] = R.WT + (size_t)lrow * IN_F + scol;
  }

  f32x4 acc[4][4];
#pragma unroll
  for (int i = 0; i < 4; ++i)
#pragma unroll
    for (int j = 0; j < 4; ++j) acc[i][j] = (f32x4){0.f, 0.f, 0.f, 0.f};

#pragma unroll 1
  for (int s = 0; s < 8; ++s) {
    const int k0 = s * 64;
#pragma unroll
    for (int i = 0; i < 4; ++i) {
      gl_lds16(ga[i] + k0, &As[(wid * 32 + i * 8) * 64]);
      gl_lds16(gb[i] + k0, &Bs[(wid * 32 + i * 8) * 64]);
    }
    __syncthreads();
#pragma unroll
    for (int kk = 0; kk < 2; ++kk) {
      const int csl = ((kk * 4 + fcol) ^ (l16 & 7)) * 8;
      short8 af[4], bf[4];
#pragma unroll
      for (int f = 0; f < 4; ++f) {
        af[f] = *(const short8*)&As[(wm + f * 16 + l16) * 64 + csl];
        bf[f] = *(const short8*)&Bs[(wn + f * 16 + l16) * 64 + csl];
      }
#pragma unroll
      for (int i = 0; i < 4; ++i)
#pragma unroll
        for (int j = 0; j < 4; ++j)
          acc[i][j] = __builtin_amdgcn_mfma_f32_16x16x32_bf16(af[i], bf[j], acc[i][j], 0, 0, 0);
    }
    __syncthreads();
  }

  const int r4 = (lane >> 4) * 4;  // C/D: col=lane&15, row=(lane>>4)*4+q
#pragma unroll
  for (int i = 0; i < 4; ++i) {
#pragma unroll
    for (int qq = 0; qq < 4; ++qq) {
      const int row = m0 + wm + i * 16 + r4 + qq;
      if (row < R.n_src) {
        const int d = R.deg_out[row];
        const float sc = rsqrtf((float)(d > 1 ? d : 1));
#pragma unroll
        for (int j = 0; j < 4; ++j) {
          const int col = wn + j * 16 + l16;
          R.y[(size_t)row * OUT_F + col] = f2bf(acc[i][j][qq] * sc);
        }
      }
    }
  }
}

// ---------------- gather-aggregate + bias + relu (pad-16 segments, tail-free) --------
struct AggRel { const int* rowstart; const int* deg; const unsigned short* csr;
                const unsigned short* y; const float* b; };
struct AggType { AggRel r[4]; int n_rels; int n_nodes; float* out; };
struct AggParams { AggType t[4]; };

__global__ __launch_bounds__(256) void k_aggregate(AggParams p) {
  const AggType& T = p.t[blockIdx.y];
  const int node = blockIdx.x * 4 + (threadIdx.x >> 6);
  if (node >= T.n_nodes) return;
  const int lane = threadIdx.x & 63;
  const int quarter = lane >> 4;
  const int c8 = (lane & 15) * 8;
  f32x2 ac2[4] = {{0.f,0.f},{0.f,0.f},{0.f,0.f},{0.f,0.f}};
  float bs[8] = {0,0,0,0,0,0,0,0};
#pragma unroll
  for (int rr = 0; rr < 4; ++rr) {
    if (rr < T.n_rels) {
      const AggRel R = T.r[rr];
      const int lo = R.rowstart[node];
      const int hi = R.rowstart[node + 1];   // lo + pad16(deg)
      f32x2 rx2[4] = {{0.f,0.f},{0.f,0.f},{0.f,0.f},{0.f,0.f}};
      for (int k = lo + quarter; k < hi; k += 16) {   // tail-free: 16 rows in flight/wave
        const int s0 = R.csr[k];
        const int s1 = R.csr[k + 4];
        const int s2 = R.csr[k + 8];
        const int s3 = R.csr[k + 12];
        const uint4 u0 = *(const uint4*)(R.y + (size_t)s0 * OUT_F + c8);
        const uint4 u1 = *(const uint4*)(R.y + (size_t)s1 * OUT_F + c8);
        const uint4 u2 = *(const uint4*)(R.y + (size_t)s2 * OUT_F + c8);
        const uint4 u3 = *(const uint4*)(R.y + (size_t)s3 * OUT_F + c8);
        acc8(rx2, u0); acc8(rx2, u1); acc8(rx2, u2); acc8(rx2, u3);
      }
      const int deg = R.deg[node];
      const float s = rsqrtf((float)(deg > 1 ? deg : 1));
      const f32x2 sc2 = {s, s};
#pragma unroll
      for (int qd = 0; qd < 4; ++qd) ac2[qd] += rx2[qd] * sc2;
      const float4 b0 = *(const float4*)(R.b + c8);
      const float4 b1 = *(const float4*)(R.b + c8 + 4);
      bs[0] += b0.x; bs[1] += b0.y; bs[2] += b0.z; bs[3] += b0.w;
      bs[4] += b1.x; bs[5] += b1.y; bs[6] += b1.z; bs[7] += b1.w;
    }
  }
  float ac[8] = {ac2[0].x, ac2[0].y, ac2[1].x, ac2[1].y,
                 ac2[2].x, ac2[2].y, ac2[3].x, ac2[3].y};
#pragma unroll
  for (int qd = 0; qd < 8; ++qd) {
    ac[qd] += __shfl_xor(ac[qd], 16);
    ac[qd] += __shfl_xor(ac[qd], 32);
    ac[qd] += bs[qd];
    ac[qd] = ac[qd] > 0.f ? ac[qd] : 0.f;
  }
  if (quarter == 0) {
    float* dst = T.out + (size_t)node * OUT_F + c8;
    float4 o0 = {ac[0], ac[1], ac[2], ac[3]};
    float4 o1 = {ac[4], ac[5], ac[6], ac[7]};
    *(float4*)dst = o0;
    *(float4*)(dst + 4) = o1;
  }
}

// ---------------- host ----------------
extern "C" void kernel_launch(void* const* d_in, const int* in_sizes, int n_in,
                              void* d_out, int out_size, void* d_ws, size_t ws_size,
                              hipStream_t stream) {
  const float* h[4];
  for (int i = 0; i < 4; ++i) h[i] = (const float*)d_in[i];
  const float* W[NREL]; const float* b[NREL];
  const int* src[NREL]; const int* dst[NREL];
  for (int r = 0; r < NREL; ++r) {
    W[r]   = (const float*)d_in[4 + 2 * r];
    b[r]   = (const float*)d_in[5 + 2 * r];
    src[r] = (const int*)d_in[24 + 2 * r];
    dst[r] = (const int*)d_in[25 + 2 * r];
  }
  float* out = (float*)d_out;

  char* ws = (char*)d_ws;
  size_t off = 0;
  auto alloc = [&](size_t bytes) -> char* {
    char* p = ws + off;
    off = (off + bytes + 255) & ~(size_t)255;
    return p;
  };
  int* degO[NREL];
  { char* base = alloc((size_t)92000 * 4); size_t o = 0;
    for (int r = 0; r < NREL; ++r) { degO[r] = (int*)(base + o); o += (size_t)kNSrc[r] * 4; } }
  int* totI[NREL];
  { char* base = alloc((size_t)92000 * 4); size_t o = 0;
    for (int r = 0; r < NREL; ++r) { totI[r] = (int*)(base + o); o += (size_t)kNDst[r] * 4; } }
  int* rowst[NREL];
  { char* base = alloc((size_t)(92000 + NREL) * 4); size_t o = 0;
    for (int r = 0; r < NREL; ++r) { rowst[r] = (int*)(base + o); o += (size_t)(kNDst[r] + 1) * 4; } }
  unsigned short* csr[NREL];
  { size_t tot = 0; for (int r = 0; r < NREL; ++r) tot += (size_t)kCsrCap[r];
    char* base = alloc(tot * 2); size_t o = 0;
    for (int r = 0; r < NREL; ++r) { csr[r] = (unsigned short*)(base + o); o += (size_t)kCsrCap[r] * 2; } }
  unsigned short* WT[NREL];
  { char* base = alloc((size_t)NREL * IN_F * OUT_F * 2); size_t o = 0;
    for (int r = 0; r < NREL; ++r) { WT[r] = (unsigned short*)(base + o); o += (size_t)IN_F * OUT_F * 2; } }
  unsigned short* hb = (unsigned short*)alloc((size_t)32000 * IN_F * 2);

  // H region and y (+1 dummy row per rel) overlap: H dead after place, y written in gemm.
  size_t hBytes = 0;
  for (int r = 0; r < NREL; ++r) hBytes += (size_t)kNblk8[r] * (kNSrc[r] + kNDst[r]) * 2;
  size_t yBytes = (size_t)(92000 + NREL) * OUT_F * 2;
  char* HY = alloc(hBytes > yBytes ? hBytes : yBytes);
  unsigned short* Hsrc[NREL]; unsigned short* Hdst[NREL];
  { size_t o = 0;
    for (int r = 0; r < NREL; ++r) { Hsrc[r] = (unsigned short*)(HY + o); o += (size_t)kNblk8[r] * kNSrc[r] * 2; }
    for (int r = 0; r < NREL; ++r) { Hdst[r] = (unsigned short*)(HY + o); o += (size_t)kNblk8[r] * kNDst[r] * 2; } }
  unsigned short* y[NREL];
  { size_t o = 0;
    for (int r = 0; r < NREL; ++r) { y[r] = (unsigned short*)(HY + o); o += (size_t)(kNSrc[r] + 1) * OUT_F * 2; } }

  // 1) fused prep: count + cvt + W^T
  PrepParams pr;
  for (int r = 0; r < NREL; ++r) {
    pr.cj[r]        = CountJob{src[r], Hsrc[r], kNEdges[r], kNSrc[r]};
    pr.cj[NREL + r] = CountJob{dst[r], Hdst[r], kNEdges[r], kNDst[r]};
  }
  for (int ty = 0; ty < 4; ++ty) {
    pr.csrc[ty] = h[ty];
    pr.cdst[ty] = hb + kHbOff[ty];
  }
  for (int r = 0; r < NREL; ++r) { pr.W[r] = W[r]; pr.WT[r] = WT[r]; }
  k_prep<<<PREP_BLOCKS, 512, 0, stream>>>(pr);

  // 2) column-sum (src) + prefix (dst)
  SBParams sb;
  for (int r = 0; r < NREL; ++r) {
    sb.j[r]        = SBJob{Hsrc[r], degO[r], kNSrc[r], kNblk8[r], 0};
    sb.j[NREL + r] = SBJob{Hdst[r], totI[r], kNDst[r], kNblk8[r], 1};
  }
  k_sumbase<<<dim3((16000 + 255) / 256, 2 * NREL), 256, 0, stream>>>(sb);

  // 3) padded scan (pure)
  ScanParams sp;
  for (int r = 0; r < NREL; ++r) sp.r[r] = ScanRel{totI[r], rowst[r], kNDst[r]};
  k_scan<<<NREL, 512, 0, stream>>>(sp);

  // 4) pad-fill (parallel, one thread per node)
  PadParams pd;
  for (int r = 0; r < NREL; ++r) pd.j[r] = PadJob{totI[r], rowst[r], csr[r], kNDst[r], kNSrc[r]};
  k_pad<<<dim3((16000 + 255) / 256, NREL), 256, 0, stream>>>(pd);

  // 5) place
  PlaceParams pp;
  for (int r = 0; r < NREL; ++r)
    pp.j[r] = PlaceJob{src[r], dst[r], Hdst[r], rowst[r], csr[r], kNEdges[r], kNDst[r]};
  k_place<<<N_PLC_CH, 1024, 0, stream>>>(pp);

  // 6) GEMM (+10 dummy-row-zero blocks)
  GemmParams gp;
  for (int r = 0; r < NREL; ++r)
    gp.r[r] = GemmRel{hb + kHbOff[kRelSrcType[r]], WT[r], y[r], degO[r], kNSrc[r]};
  k_gemm<<<GEMM_JOBS + NREL, 256, 0, stream>>>(gp);

  // 7) aggregate (tail-free)
  AggParams ap;
  for (int ti = 0; ti < 4; ++ti) {
    AggType& T = ap.t[ti];
    T.n_nodes = kNNodes[ti];
    T.n_rels = kNDstRels[ti];
    T.out = out + kOutOff[ti];
    for (int j = 0; j < 4; ++j) {
      int r = kDstRels[ti][j];
      if (r < 0) r = kDstRels[ti][0];
      T.r[j] = AggRel{rowst[r], totI[r], csr[r], y[r], b[r]};
    }
  }
  k_aggregate<<<dim3((16000 + 3) / 4, 4), 256, 0, stream>>>(ap);
}

// Round 16
// 182.624 us; speedup vs baseline: 1.2710x; 1.0677x over previous
//
#include <hip/hip_runtime.h>
#include <cstddef>
#include <cstdint>

#define IN_F 512
#define OUT_F 128
#define NREL 10
#define MAXBINS 16000

typedef __attribute__((ext_vector_type(8))) short short8;
typedef __attribute__((ext_vector_type(4))) float f32x4;
typedef float f32x2 __attribute__((ext_vector_type(2)));

static const int kNSrc[NREL]   = {8000,16000,8000,16000,8000,4000,8000,4000,16000,4000};
static const int kNDst[NREL]   = {8000,16000,16000,8000,4000,8000,4000,8000,4000,16000};
static const int kNEdges[NREL] = {200000,800000,400000,400000,100000,100000,100000,100000,150000,150000};
static const int kRelSrcType[NREL] = {0,1,0,1,0,2,0,3,1,2};
static const int kNNodes[4] = {8000,16000,4000,4000};
static const size_t kOutOff[4] = {0, 8000ull*OUT_F, 24000ull*OUT_F, 28000ull*OUT_F};
static const size_t kHOff[4] = {0, 8000ull*IN_F, 24000ull*IN_F, 28000ull*IN_F};
static const int kDstRels[4][4] = {{0,3,5,7},{1,2,9,-1},{4,8,-1,-1},{6,-1,-1,-1}};
static const int kNDstRels[4] = {4,3,2,1};
static const int kNblk8[NREL] = {25,98,49,49,13,13,13,13,19,19};   // ceil(E/8192), sum 311
// padded csr capacity per rel: E + 16*n_dst
static const int kCsrCap[NREL] = {328000,1056000,656000,528000,164000,228000,164000,228000,214000,406000};

// count chunks (8192): jobs 0..9 = src, 10..19 = dst
__device__ const int kCntCum[21] = {0,25,123,172,221,234,247,260,273,292,311,
                                    336,434,483,532,545,558,571,584,603,622};
#define N_CNT_CH 622
#define N_WT_CH  80
#define PREP_BLOCKS (N_CNT_CH + N_WT_CH)   // 702
// place chunks (8192)
__device__ const int kPlcCum[11] = {0,25,123,172,221,234,247,260,273,292,311};
#define N_PLC_CH 311

__device__ __forceinline__ unsigned short f2bf(float f) {
  union { float f; unsigned u; } v; v.f = f;
  unsigned r = v.u + 0x7fffu + ((v.u >> 16) & 1u);
  return (unsigned short)(r >> 16);
}
// unpack uint4 (8 bf16) -> 4 f32 pairs, accumulate
__device__ __forceinline__ void acc8(f32x2* a, uint4 u) {
  union { unsigned v; float f; } lo0, hi0, lo1, hi1, lo2, hi2, lo3, hi3;
  lo0.v = u.x << 16; hi0.v = u.x & 0xffff0000u;
  lo1.v = u.y << 16; hi1.v = u.y & 0xffff0000u;
  lo2.v = u.z << 16; hi2.v = u.z & 0xffff0000u;
  lo3.v = u.w << 16; hi3.v = u.w & 0xffff0000u;
  a[0] += (f32x2){lo0.f, hi0.f};
  a[1] += (f32x2){lo1.f, hi1.f};
  a[2] += (f32x2){lo2.f, hi2.f};
  a[3] += (f32x2){lo3.f, hi3.f};
}
// async global->LDS, 16B/lane (m97 pattern)
__device__ __forceinline__ void gl_lds16(const void* g, const void* l) {
  __builtin_amdgcn_global_load_lds(
      (const __attribute__((address_space(1))) unsigned int*)(g),
      (__attribute__((address_space(3))) unsigned int*)(l), 16, 0, 0);
}

// ---------------- fused prep: count(0..621) | WT(622..701) ---------------------------
struct CountJob { const int* idx; unsigned short* H; int n_edges; int nbins; };
struct PrepParams {
  CountJob cj[2 * NREL];
  const float* W[NREL]; unsigned short* WT[NREL];
};

__global__ __launch_bounds__(512) void k_prep(PrepParams p) {
  __shared__ unsigned lb[MAXBINS / 2];
  const int c = blockIdx.x;
  const int t = threadIdx.x;
  if (c < N_CNT_CH) {
    int j = 0;
    while (c >= kCntCum[j + 1]) ++j;
    const CountJob J = p.cj[j];
    const int ch = c - kCntCum[j];
    const int e0 = ch * 8192;
    const int eend = (e0 + 8192 < J.n_edges) ? e0 + 8192 : J.n_edges;
    const int nw = J.nbins >> 1;
    for (int d = t; d < nw; d += 512) lb[d] = 0;
    __syncthreads();
    for (int e = e0 + t * 4; e < eend; e += 2048) {
      const int4 v = *(const int4*)(J.idx + e);
      atomicAdd(&lb[v.x >> 1], 1u << ((v.x & 1) << 4));
      atomicAdd(&lb[v.y >> 1], 1u << ((v.y & 1) << 4));
      atomicAdd(&lb[v.z >> 1], 1u << ((v.z & 1) << 4));
      atomicAdd(&lb[v.w >> 1], 1u << ((v.w & 1) << 4));
    }
    __syncthreads();
    unsigned short* Hrow = J.H + (size_t)ch * J.nbins;
    for (int d = t; d < nw; d += 512) *(unsigned*)&Hrow[d * 2] = lb[d];
  } else {
    const int u = c - N_CNT_CH;
    const int r = u >> 3;
    const int g0 = (u & 7) * 2048;
    const float* W = p.W[r];
    unsigned short* WT = p.WT[r];
    for (int g = g0 + t; g < g0 + 2048; g += 512) {
      const int k = g >> 5;
      const int n0 = (g & 31) * 4;
      const float4 w = *(const float4*)(W + (size_t)k * OUT_F + n0);
      WT[(size_t)(n0 + 0) * IN_F + k] = f2bf(w.x);
      WT[(size_t)(n0 + 1) * IN_F + k] = f2bf(w.y);
      WT[(size_t)(n0 + 2) * IN_F + k] = f2bf(w.z);
      WT[(size_t)(n0 + 3) * IN_F + k] = f2bf(w.w);
    }
  }
}

// ---------------- fused column-sum (src) + per-bin prefix (dst) over H ---------------
struct SBJob { unsigned short* H; int* tot; int nbins; int nblocks; int prefix; };
struct SBParams { SBJob j[2 * NREL]; };

__global__ __launch_bounds__(256) void k_sumbase(SBParams p) {
  SBJob J = p.j[blockIdx.y];
  const int bin = blockIdx.x * 256 + threadIdx.x;
  if (bin >= J.nbins) return;
  int run = 0;
  if (J.prefix) {
    for (int b = 0; b < J.nblocks; ++b) {
      const size_t o = (size_t)b * J.nbins + bin;
      const int cc = J.H[o];
      J.H[o] = (unsigned short)run;
      run += cc;
    }
  } else {
    for (int b = 0; b < J.nblocks; ++b) run += J.H[(size_t)b * J.nbins + bin];
  }
  J.tot[bin] = run;
}

// ---------------- exclusive scan over PADDED counts (pure scan) ----------------------
struct ScanRel { const int* tot; int* rowstart; int n; };
struct ScanParams { ScanRel r[NREL]; };

__global__ __launch_bounds__(512) void k_scan(ScanParams p) {
  ScanRel R = p.r[blockIdx.x];
  const int t = threadIdx.x;
  const int lane = t & 63, wv = t >> 6;
  const int base = t * 32;
  int v[32];
  int s = 0;
#pragma unroll
  for (int i = 0; i < 32; ++i) {
    int e = base + i;
    int x = (e < R.n) ? R.tot[e] : 0;
    int xp = (x + 15) & ~15;          // pad segment to multiple of 16
    v[i] = s; s += xp;
  }
  int inc = s;
#pragma unroll
  for (int off = 1; off < 64; off <<= 1) {
    int u = __shfl_up(inc, off);
    if (lane >= off) inc += u;
  }
  __shared__ int wsum[8];
  if (lane == 63) wsum[wv] = inc;
  __syncthreads();
  int carry = 0, total = 0;
#pragma unroll
  for (int w = 0; w < 8; ++w) {
    int x = wsum[w];
    if (w < wv) carry += x;
    total += x;
  }
  const int tb = carry + (inc - s);
#pragma unroll
  for (int i = 0; i < 32; ++i) {
    int e = base + i;
    if (e < R.n) R.rowstart[e] = tb + v[i];
  }
  if (t == 0) R.rowstart[R.n] = total;
}

// ---------------- pad-fill: one thread per dst node ----------------------------------
struct PadJob { const int* tot; const int* rowstart; unsigned short* csr; int nbins; int dummy; };
struct PadParams { PadJob j[NREL]; };

__global__ __launch_bounds__(256) void k_pad(PadParams p) {
  const PadJob J = p.j[blockIdx.y];
  const int bin = blockIdx.x * 256 + threadIdx.x;
  if (bin >= J.nbins) return;
  const int x = J.tot[bin];
  const int xp = (x + 15) & ~15;
  const int lo = J.rowstart[bin];
  const unsigned short d = (unsigned short)J.dummy;
  for (int pk = x; pk < xp; ++pk) J.csr[lo + pk] = d;
}

// ---------------- place: 8192-edge chunks, LDS cursors -------------------------------
struct PlaceJob { const int* src; const int* dst; const unsigned short* Hpre; const int* rowstart;
                  unsigned short* csr; int n_edges; int nbins; };
struct PlaceParams { PlaceJob j[NREL]; };

__global__ __launch_bounds__(1024) void k_place(PlaceParams p) {
  __shared__ int lb[MAXBINS];
  const int c = blockIdx.x;
  const int t = threadIdx.x;
  int j = 0;
  while (c >= kPlcCum[j + 1]) ++j;
  const PlaceJob J = p.j[j];
  const int ch = c - kPlcCum[j];
  const int e0 = ch * 8192;
  const int eend = (e0 + 8192 < J.n_edges) ? e0 + 8192 : J.n_edges;
  const unsigned short* Hrow = J.Hpre + (size_t)ch * J.nbins;
  for (int d = t; d < J.nbins; d += 1024) lb[d] = J.rowstart[d] + (int)Hrow[d];
  __syncthreads();
  for (int e = e0 + t * 4; e < eend; e += 4096) {
    const int4 dv = *(const int4*)(J.dst + e);
    const int4 sv = *(const int4*)(J.src + e);
    const int p0 = atomicAdd(&lb[dv.x], 1); J.csr[p0] = (unsigned short)sv.x;
    const int p1 = atomicAdd(&lb[dv.y], 1); J.csr[p1] = (unsigned short)sv.y;
    const int p2 = atomicAdd(&lb[dv.z], 1); J.csr[p2] = (unsigned short)sv.z;
    const int p3 = atomicAdd(&lb[dv.w], 1); J.csr[p3] = (unsigned short)sv.w;
  }
}

// ---------------- y_r = (h @ W_r) * deg_out^-1/2 — f32-A gload_lds + cvt_pk MFMA -----
// A staged as f32 directly from h (no bf16 pre-pass): 32KB tile, 16B-slot XOR swizzle
// (slot ^ row&7, inverse-swizzled global source per rule #21). Fragments converted
// after ds_read via v_cvt_pk_bf16_f32 (T12-verified inline asm). B = bf16 WT as before.
struct GemmRel { const float* h; const unsigned short* WT; unsigned short* y;
                 const int* deg_out; int n_src; };
struct GemmParams { GemmRel r[NREL]; };

#define GEMM_JOBS 723

__global__ __launch_bounds__(256) void k_gemm(GemmParams p) {
  if (blockIdx.x >= GEMM_JOBS) {
    const int r = blockIdx.x - GEMM_JOBS;
    if (threadIdx.x < 64)
      ((unsigned*)(p.r[r].y + (size_t)p.r[r].n_src * OUT_F))[threadIdx.x] = 0u;
    return;
  }
  // bijective XCD swizzle: orig -> jobid (m204)
  const int orig = blockIdx.x;
  const int xcd = orig & 7;
  const int i8 = orig >> 3;
  const int q = GEMM_JOBS / 8, rm = GEMM_JOBS % 8;   // 90, 3
  const int g = (xcd < rm ? xcd * (q + 1) : rm * (q + 1) + (xcd - rm) * q) + i8;
  static const int dr[4] = {0, 2, 4, 6};
  static const int pr[3] = {1, 3, 8};
  static const int xr[2] = {5, 9};
  int rel, tile;
  if (g < 252)      { rel = dr[g & 3]; tile = g >> 2; }
  else if (g < 627) { int u = g - 252; rel = pr[u % 3]; tile = u / 3; }
  else if (g < 691) { int u = g - 627; rel = xr[u & 1]; tile = u >> 1; }
  else              { rel = 7; tile = g - 691; }

  const GemmRel R = p.r[rel];
  const int m0 = tile * 128;

  __shared__ float Af[128 * 64];            // 32 KB: [row][64 f32], 16 slots x 16B
  __shared__ unsigned short Bs[128 * 64];   // 16 KB: [row][64 bf16], 8 slots x 16B

  const int t = threadIdx.x;
  const int lane = t & 63, wid = t >> 6;
  const int wm = (wid >> 1) * 64, wn = (wid & 1) * 64;
  const int l16 = lane & 15;
  const int x7 = l16 & 7;
  const int fcol = lane >> 4;

  // A staging: 8 issues of 16 rows; wave covers 4 rows (lane>>4), slot16 = lane&15
  const int arowl = wid * 4 + (lane >> 4);     // row within 16-row issue group
  const int aslot = lane & 15;
  const float* ga[8];
#pragma unroll
  for (int i = 0; i < 8; ++i) {
    int grow = m0 + i * 16 + arowl;
    if (grow > R.n_src - 1) grow = R.n_src - 1;   // clamp: finite garbage, not stored
    ga[i] = R.h + (size_t)grow * IN_F + (size_t)((aslot ^ (arowl & 7)) * 4);
  }
  // B staging (bf16, unchanged): 4 issues of 32 rows; 8 rows/wave, slot8 = lane&7
  const int srow8 = lane >> 3;
  const int slot8 = lane & 7;
  const unsigned short* gb[4];
#pragma unroll
  for (int i = 0; i < 4; ++i) {
    const int lrow = wid * 32 + i * 8 + srow8;
    gb[i] = R.WT + (size_t)lrow * IN_F + (size_t)((slot8 ^ srow8) * 8);
  }

  f32x4 acc[4][4];
#pragma unroll
  for (int i = 0; i < 4; ++i)
#pragma unroll
    for (int j = 0; j < 4; ++j) acc[i][j] = (f32x4){0.f, 0.f, 0.f, 0.f};

#pragma unroll 1
  for (int s = 0; s < 8; ++s) {
    const int k0 = s * 64;   // 64 elems per K-step (f32 for A, bf16 for B)
#pragma unroll
    for (int i = 0; i < 8; ++i)
      gl_lds16(ga[i] + k0, &Af[(i * 16 + wid * 4) * 64]);
#pragma unroll
    for (int i = 0; i < 4; ++i)
      gl_lds16(gb[i] + k0, &Bs[(wid * 32 + i * 8) * 64]);
    __syncthreads();
#pragma unroll
    for (int kk = 0; kk < 2; ++kk) {
      short8 af[4], bf[4];
      const int s0 = kk * 8 + fcol * 2;        // A: first of two f32 slots
      const int csl = ((kk * 4 + fcol) ^ x7) * 8;  // B: swizzled bf16 slot offset
#pragma unroll
      for (int f = 0; f < 4; ++f) {
        const int Ra = wm + f * 16 + l16;
        const float4 a0 = *(const float4*)&Af[Ra * 64 + ((s0 ^ x7) * 4)];
        const float4 a1 = *(const float4*)&Af[Ra * 64 + (((s0 + 1) ^ x7) * 4)];
        union { unsigned u[4]; short8 s8; } cv;
        asm("v_cvt_pk_bf16_f32 %0, %1, %2" : "=v"(cv.u[0]) : "v"(a0.x), "v"(a0.y));
        asm("v_cvt_pk_bf16_f32 %0, %1, %2" : "=v"(cv.u[1]) : "v"(a0.z), "v"(a0.w));
        asm("v_cvt_pk_bf16_f32 %0, %1, %2" : "=v"(cv.u[2]) : "v"(a1.x), "v"(a1.y));
        asm("v_cvt_pk_bf16_f32 %0, %1, %2" : "=v"(cv.u[3]) : "v"(a1.z), "v"(a1.w));
        af[f] = cv.s8;
        bf[f] = *(const short8*)&Bs[(wn + f * 16 + l16) * 64 + csl];
      }
#pragma unroll
      for (int i = 0; i < 4; ++i)
#pragma unroll
        for (int j = 0; j < 4; ++j)
          acc[i][j] = __builtin_amdgcn_mfma_f32_16x16x32_bf16(af[i], bf[j], acc[i][j], 0, 0, 0);
    }
    __syncthreads();
  }

  const int r4 = (lane >> 4) * 4;  // C/D: col=lane&15, row=(lane>>4)*4+q
#pragma unroll
  for (int i = 0; i < 4; ++i) {
#pragma unroll
    for (int qq = 0; qq < 4; ++qq) {
      const int row = m0 + wm + i * 16 + r4 + qq;
      if (row < R.n_src) {
        const int d = R.deg_out[row];
        const float sc = rsqrtf((float)(d > 1 ? d : 1));
#pragma unroll
        for (int j = 0; j < 4; ++j) {
          const int col = wn + j * 16 + l16;
          R.y[(size_t)row * OUT_F + col] = f2bf(acc[i][j][qq] * sc);
        }
      }
    }
  }
}

// ---------------- gather-aggregate + bias + relu (pad-16 segments, tail-free) --------
struct AggRel { const int* rowstart; const int* deg; const unsigned short* csr;
                const unsigned short* y; const float* b; };
struct AggType { AggRel r[4]; int n_rels; int n_nodes; float* out; };
struct AggParams { AggType t[4]; };

__global__ __launch_bounds__(256) void k_aggregate(AggParams p) {
  const AggType& T = p.t[blockIdx.y];
  const int node = blockIdx.x * 4 + (threadIdx.x >> 6);
  if (node >= T.n_nodes) return;
  const int lane = threadIdx.x & 63;
  const int quarter = lane >> 4;
  const int c8 = (lane & 15) * 8;
  f32x2 ac2[4] = {{0.f,0.f},{0.f,0.f},{0.f,0.f},{0.f,0.f}};
  float bs[8] = {0,0,0,0,0,0,0,0};
#pragma unroll
  for (int rr = 0; rr < 4; ++rr) {
    if (rr < T.n_rels) {
      const AggRel R = T.r[rr];
      const int lo = R.rowstart[node];
      const int hi = R.rowstart[node + 1];   // lo + pad16(deg)
      f32x2 rx2[4] = {{0.f,0.f},{0.f,0.f},{0.f,0.f},{0.f,0.f}};
      for (int k = lo + quarter; k < hi; k += 16) {   // tail-free
        const int s0 = R.csr[k];
        const int s1 = R.csr[k + 4];
        const int s2 = R.csr[k + 8];
        const int s3 = R.csr[k + 12];
        const uint4 u0 = *(const uint4*)(R.y + (size_t)s0 * OUT_F + c8);
        const uint4 u1 = *(const uint4*)(R.y + (size_t)s1 * OUT_F + c8);
        const uint4 u2 = *(const uint4*)(R.y + (size_t)s2 * OUT_F + c8);
        const uint4 u3 = *(const uint4*)(R.y + (size_t)s3 * OUT_F + c8);
        acc8(rx2, u0); acc8(rx2, u1); acc8(rx2, u2); acc8(rx2, u3);
      }
      const int deg = R.deg[node];
      const float s = rsqrtf((float)(deg > 1 ? deg : 1));
      const f32x2 sc2 = {s, s};
#pragma unroll
      for (int qd = 0; qd < 4; ++qd) ac2[qd] += rx2[qd] * sc2;
      const float4 b0 = *(const float4*)(R.b + c8);
      const float4 b1 = *(const float4*)(R.b + c8 + 4);
      bs[0] += b0.x; bs[1] += b0.y; bs[2] += b0.z; bs[3] += b0.w;
      bs[4] += b1.x; bs[5] += b1.y; bs[6] += b1.z; bs[7] += b1.w;
    }
  }
  float ac[8] = {ac2[0].x, ac2[0].y, ac2[1].x, ac2[1].y,
                 ac2[2].x, ac2[2].y, ac2[3].x, ac2[3].y};
#pragma unroll
  for (int qd = 0; qd < 8; ++qd) {
    ac[qd] += __shfl_xor(ac[qd], 16);
    ac[qd] += __shfl_xor(ac[qd], 32);
    ac[qd] += bs[qd];
    ac[qd] = ac[qd] > 0.f ? ac[qd] : 0.f;
  }
  if (quarter == 0) {
    float* dst = T.out + (size_t)node * OUT_F + c8;
    float4 o0 = {ac[0], ac[1], ac[2], ac[3]};
    float4 o1 = {ac[4], ac[5], ac[6], ac[7]};
    *(float4*)dst = o0;
    *(float4*)(dst + 4) = o1;
  }
}

// ---------------- host ----------------
extern "C" void kernel_launch(void* const* d_in, const int* in_sizes, int n_in,
                              void* d_out, int out_size, void* d_ws, size_t ws_size,
                              hipStream_t stream) {
  const float* h[4];
  for (int i = 0; i < 4; ++i) h[i] = (const float*)d_in[i];
  const float* W[NREL]; const float* b[NREL];
  const int* src[NREL]; const int* dst[NREL];
  for (int r = 0; r < NREL; ++r) {
    W[r]   = (const float*)d_in[4 + 2 * r];
    b[r]   = (const float*)d_in[5 + 2 * r];
    src[r] = (const int*)d_in[24 + 2 * r];
    dst[r] = (const int*)d_in[25 + 2 * r];
  }
  float* out = (float*)d_out;

  char* ws = (char*)d_ws;
  size_t off = 0;
  auto alloc = [&](size_t bytes) -> char* {
    char* p = ws + off;
    off = (off + bytes + 255) & ~(size_t)255;
    return p;
  };
  int* degO[NREL];
  { char* base = alloc((size_t)92000 * 4); size_t o = 0;
    for (int r = 0; r < NREL; ++r) { degO[r] = (int*)(base + o); o += (size_t)kNSrc[r] * 4; } }
  int* totI[NREL];
  { char* base = alloc((size_t)92000 * 4); size_t o = 0;
    for (int r = 0; r < NREL; ++r) { totI[r] = (int*)(base + o); o += (size_t)kNDst[r] * 4; } }
  int* rowst[NREL];
  { char* base = alloc((size_t)(92000 + NREL) * 4); size_t o = 0;
    for (int r = 0; r < NREL; ++r) { rowst[r] = (int*)(base + o); o += (size_t)(kNDst[r] + 1) * 4; } }
  unsigned short* csr[NREL];
  { size_t tot = 0; for (int r = 0; r < NREL; ++r) tot += (size_t)kCsrCap[r];
    char* base = alloc(tot * 2); size_t o = 0;
    for (int r = 0; r < NREL; ++r) { csr[r] = (unsigned short*)(base + o); o += (size_t)kCsrCap[r] * 2; } }
  unsigned short* WT[NREL];
  { char* base = alloc((size_t)NREL * IN_F * OUT_F * 2); size_t o = 0;
    for (int r = 0; r < NREL; ++r) { WT[r] = (unsigned short*)(base + o); o += (size_t)IN_F * OUT_F * 2; } }

  // H region and y (+1 dummy row per rel) overlap: H dead after place, y written in gemm.
  size_t hBytes = 0;
  for (int r = 0; r < NREL; ++r) hBytes += (size_t)kNblk8[r] * (kNSrc[r] + kNDst[r]) * 2;
  size_t yBytes = (size_t)(92000 + NREL) * OUT_F * 2;
  char* HY = alloc(hBytes > yBytes ? hBytes : yBytes);
  unsigned short* Hsrc[NREL]; unsigned short* Hdst[NREL];
  { size_t o = 0;
    for (int r = 0; r < NREL; ++r) { Hsrc[r] = (unsigned short*)(HY + o); o += (size_t)kNblk8[r] * kNSrc[r] * 2; }
    for (int r = 0; r < NREL; ++r) { Hdst[r] = (unsigned short*)(HY + o); o += (size_t)kNblk8[r] * kNDst[r] * 2; } }
  unsigned short* y[NREL];
  { size_t o = 0;
    for (int r = 0; r < NREL; ++r) { y[r] = (unsigned short*)(HY + o); o += (size_t)(kNSrc[r] + 1) * OUT_F * 2; } }

  // 1) fused prep: count + W^T
  PrepParams pr;
  for (int r = 0; r < NREL; ++r) {
    pr.cj[r]        = CountJob{src[r], Hsrc[r], kNEdges[r], kNSrc[r]};
    pr.cj[NREL + r] = CountJob{dst[r], Hdst[r], kNEdges[r], kNDst[r]};
  }
  for (int r = 0; r < NREL; ++r) { pr.W[r] = W[r]; pr.WT[r] = WT[r]; }
  k_prep<<<PREP_BLOCKS, 512, 0, stream>>>(pr);

  // 2) column-sum (src) + prefix (dst)
  SBParams sb;
  for (int r = 0; r < NREL; ++r) {
    sb.j[r]        = SBJob{Hsrc[r], degO[r], kNSrc[r], kNblk8[r], 0};
    sb.j[NREL + r] = SBJob{Hdst[r], totI[r], kNDst[r], kNblk8[r], 1};
  }
  k_sumbase<<<dim3((16000 + 255) / 256, 2 * NREL), 256, 0, stream>>>(sb);

  // 3) padded scan (pure)
  ScanParams sp;
  for (int r = 0; r < NREL; ++r) sp.r[r] = ScanRel{totI[r], rowst[r], kNDst[r]};
  k_scan<<<NREL, 512, 0, stream>>>(sp);

  // 4) pad-fill
  PadParams pd;
  for (int r = 0; r < NREL; ++r) pd.j[r] = PadJob{totI[r], rowst[r], csr[r], kNDst[r], kNSrc[r]};
  k_pad<<<dim3((16000 + 255) / 256, NREL), 256, 0, stream>>>(pd);

  // 5) place
  PlaceParams pp;
  for (int r = 0; r < NREL; ++r)
    pp.j[r] = PlaceJob{src[r], dst[r], Hdst[r], rowst[r], csr[r], kNEdges[r], kNDst[r]};
  k_place<<<N_PLC_CH, 1024, 0, stream>>>(pp);

  // 6) GEMM (f32-A direct; +10 dummy-row-zero blocks)
  GemmParams gp;
  for (int r = 0; r < NREL; ++r)
    gp.r[r] = GemmRel{h[kRelSrcType[r]], WT[r], y[r], degO[r], kNSrc[r]};
  k_gemm<<<GEMM_JOBS + NREL, 256, 0, stream>>>(gp);

  // 7) aggregate (tail-free)
  AggParams ap;
  for (int ti = 0; ti < 4; ++ti) {
    AggType& T = ap.t[ti];
    T.n_nodes = kNNodes[ti];
    T.n_rels = kNDstRels[ti];
    T.out = out + kOutOff[ti];
    for (int j = 0; j < 4; ++j) {
      int r = kDstRels[ti][j];
      if (r < 0) r = kDstRels[ti][0];
      T.r[j] = AggRel{rowst[r], totI[r], csr[r], y[r], b[r]};
    }
  }
  k_aggregate<<<dim3((16000 + 3) / 4, 4), 256, 0, stream>>>(ap);
}

// Round 17
// 174.611 us; speedup vs baseline: 1.3293x; 1.0459x over previous
//
#include <hip/hip_runtime.h>
#include <cstddef>
#include <cstdint>

#define IN_F 512
#define OUT_F 128
#define NREL 10
#define MAXBINS 16000

typedef __attribute__((ext_vector_type(8))) short short8;
typedef __attribute__((ext_vector_type(4))) float f32x4;
typedef float f32x2 __attribute__((ext_vector_type(2)));

static const int kNSrc[NREL]   = {8000,16000,8000,16000,8000,4000,8000,4000,16000,4000};
static const int kNDst[NREL]   = {8000,16000,16000,8000,4000,8000,4000,8000,4000,16000};
static const int kNEdges[NREL] = {200000,800000,400000,400000,100000,100000,100000,100000,150000,150000};
static const int kRelSrcType[NREL] = {0,1,0,1,0,2,0,3,1,2};
static const int kNNodes[4] = {8000,16000,4000,4000};
static const size_t kOutOff[4] = {0, 8000ull*OUT_F, 24000ull*OUT_F, 28000ull*OUT_F};
static const size_t kHOff[4] = {0, 8000ull*IN_F, 24000ull*IN_F, 28000ull*IN_F};
static const int kDstRels[4][4] = {{0,3,5,7},{1,2,9,-1},{4,8,-1,-1},{6,-1,-1,-1}};
static const int kNDstRels[4] = {4,3,2,1};
static const int kNblk8[NREL] = {25,98,49,49,13,13,13,13,19,19};   // ceil(E/8192), sum 311
// padded csr capacity per rel: E + 16*n_dst
static const int kCsrCap[NREL] = {328000,1056000,656000,528000,164000,228000,164000,228000,214000,406000};

// count chunks (8192): jobs 0..9 = src, 10..19 = dst
__device__ const int kCntCum[21] = {0,25,123,172,221,234,247,260,273,292,311,
                                    336,434,483,532,545,558,571,584,603,622};
#define N_CNT_CH 622
#define N_WT_CH  80
#define PREP_BLOCKS (N_CNT_CH + N_WT_CH)   // 702
// place chunks (8192)
__device__ const int kPlcCum[11] = {0,25,123,172,221,234,247,260,273,292,311};
#define N_PLC_CH 311

__device__ __forceinline__ unsigned short f2bf(float f) {
  union { float f; unsigned u; } v; v.f = f;
  unsigned r = v.u + 0x7fffu + ((v.u >> 16) & 1u);
  return (unsigned short)(r >> 16);
}
// unpack uint4 (8 bf16) -> 4 f32 pairs, accumulate
__device__ __forceinline__ void acc8(f32x2* a, uint4 u) {
  union { unsigned v; float f; } lo0, hi0, lo1, hi1, lo2, hi2, lo3, hi3;
  lo0.v = u.x << 16; hi0.v = u.x & 0xffff0000u;
  lo1.v = u.y << 16; hi1.v = u.y & 0xffff0000u;
  lo2.v = u.z << 16; hi2.v = u.z & 0xffff0000u;
  lo3.v = u.w << 16; hi3.v = u.w & 0xffff0000u;
  a[0] += (f32x2){lo0.f, hi0.f};
  a[1] += (f32x2){lo1.f, hi1.f};
  a[2] += (f32x2){lo2.f, hi2.f};
  a[3] += (f32x2){lo3.f, hi3.f};
}
// async global->LDS, 16B/lane (m97 pattern)
__device__ __forceinline__ void gl_lds16(const void* g, const void* l) {
  __builtin_amdgcn_global_load_lds(
      (const __attribute__((address_space(1))) unsigned int*)(g),
      (__attribute__((address_space(3))) unsigned int*)(l), 16, 0, 0);
}

// ---------------- fused prep: count(0..621) | WT(622..701) ---------------------------
struct CountJob { const int* idx; unsigned short* H; int n_edges; int nbins; };
struct PrepParams {
  CountJob cj[2 * NREL];
  const float* W[NREL]; unsigned short* WT[NREL];
};

__global__ __launch_bounds__(512) void k_prep(PrepParams p) {
  __shared__ unsigned lb[MAXBINS / 2];
  const int c = blockIdx.x;
  const int t = threadIdx.x;
  if (c < N_CNT_CH) {
    int j = 0;
    while (c >= kCntCum[j + 1]) ++j;
    const CountJob J = p.cj[j];
    const int ch = c - kCntCum[j];
    const int e0 = ch * 8192;
    const int eend = (e0 + 8192 < J.n_edges) ? e0 + 8192 : J.n_edges;
    const int nw = J.nbins >> 1;
    for (int d = t; d < nw; d += 512) lb[d] = 0;
    __syncthreads();
    for (int e = e0 + t * 4; e < eend; e += 2048) {
      const int4 v = *(const int4*)(J.idx + e);
      atomicAdd(&lb[v.x >> 1], 1u << ((v.x & 1) << 4));
      atomicAdd(&lb[v.y >> 1], 1u << ((v.y & 1) << 4));
      atomicAdd(&lb[v.z >> 1], 1u << ((v.z & 1) << 4));
      atomicAdd(&lb[v.w >> 1], 1u << ((v.w & 1) << 4));
    }
    __syncthreads();
    unsigned short* Hrow = J.H + (size_t)ch * J.nbins;
    for (int d = t; d < nw; d += 512) *(unsigned*)&Hrow[d * 2] = lb[d];
  } else {
    const int u = c - N_CNT_CH;
    const int r = u >> 3;
    const int g0 = (u & 7) * 2048;
    const float* W = p.W[r];
    unsigned short* WT = p.WT[r];
    for (int g = g0 + t; g < g0 + 2048; g += 512) {
      const int k = g >> 5;
      const int n0 = (g & 31) * 4;
      const float4 w = *(const float4*)(W + (size_t)k * OUT_F + n0);
      WT[(size_t)(n0 + 0) * IN_F + k] = f2bf(w.x);
      WT[(size_t)(n0 + 1) * IN_F + k] = f2bf(w.y);
      WT[(size_t)(n0 + 2) * IN_F + k] = f2bf(w.z);
      WT[(size_t)(n0 + 3) * IN_F + k] = f2bf(w.w);
    }
  }
}

// ---------------- fused column-sum (src) + per-bin prefix (dst) over H ---------------
struct SBJob { unsigned short* H; int* tot; int nbins; int nblocks; int prefix; };
struct SBParams { SBJob j[2 * NREL]; };

__global__ __launch_bounds__(256) void k_sumbase(SBParams p) {
  SBJob J = p.j[blockIdx.y];
  const int bin = blockIdx.x * 256 + threadIdx.x;
  if (bin >= J.nbins) return;
  int run = 0;
  if (J.prefix) {
    for (int b = 0; b < J.nblocks; ++b) {
      const size_t o = (size_t)b * J.nbins + bin;
      const int cc = J.H[o];
      J.H[o] = (unsigned short)run;
      run += cc;
    }
  } else {
    for (int b = 0; b < J.nblocks; ++b) run += J.H[(size_t)b * J.nbins + bin];
  }
  J.tot[bin] = run;
}

// ---------------- exclusive scan over PADDED counts (pure scan) ----------------------
struct ScanRel { const int* tot; int* rowstart; int n; };
struct ScanParams { ScanRel r[NREL]; };

__global__ __launch_bounds__(512) void k_scan(ScanParams p) {
  ScanRel R = p.r[blockIdx.x];
  const int t = threadIdx.x;
  const int lane = t & 63, wv = t >> 6;
  const int base = t * 32;
  int v[32];
  int s = 0;
#pragma unroll
  for (int i = 0; i < 32; ++i) {
    int e = base + i;
    int x = (e < R.n) ? R.tot[e] : 0;
    int xp = (x + 15) & ~15;          // pad segment to multiple of 16
    v[i] = s; s += xp;
  }
  int inc = s;
#pragma unroll
  for (int off = 1; off < 64; off <<= 1) {
    int u = __shfl_up(inc, off);
    if (lane >= off) inc += u;
  }
  __shared__ int wsum[8];
  if (lane == 63) wsum[wv] = inc;
  __syncthreads();
  int carry = 0, total = 0;
#pragma unroll
  for (int w = 0; w < 8; ++w) {
    int x = wsum[w];
    if (w < wv) carry += x;
    total += x;
  }
  const int tb = carry + (inc - s);
#pragma unroll
  for (int i = 0; i < 32; ++i) {
    int e = base + i;
    if (e < R.n) R.rowstart[e] = tb + v[i];
  }
  if (t == 0) R.rowstart[R.n] = total;
}

// ---------------- pad-fill: one thread per dst node ----------------------------------
struct PadJob { const int* tot; const int* rowstart; unsigned short* csr; int nbins; int dummy; };
struct PadParams { PadJob j[NREL]; };

__global__ __launch_bounds__(256) void k_pad(PadParams p) {
  const PadJob J = p.j[blockIdx.y];
  const int bin = blockIdx.x * 256 + threadIdx.x;
  if (bin >= J.nbins) return;
  const int x = J.tot[bin];
  const int xp = (x + 15) & ~15;
  const int lo = J.rowstart[bin];
  const unsigned short d = (unsigned short)J.dummy;
  for (int pk = x; pk < xp; ++pk) J.csr[lo + pk] = d;
}

// ---------------- place: 8192-edge chunks, LDS cursors -------------------------------
struct PlaceJob { const int* src; const int* dst; const unsigned short* Hpre; const int* rowstart;
                  unsigned short* csr; int n_edges; int nbins; };
struct PlaceParams { PlaceJob j[NREL]; };

__global__ __launch_bounds__(1024) void k_place(PlaceParams p) {
  __shared__ int lb[MAXBINS];
  const int c = blockIdx.x;
  const int t = threadIdx.x;
  int j = 0;
  while (c >= kPlcCum[j + 1]) ++j;
  const PlaceJob J = p.j[j];
  const int ch = c - kPlcCum[j];
  const int e0 = ch * 8192;
  const int eend = (e0 + 8192 < J.n_edges) ? e0 + 8192 : J.n_edges;
  const unsigned short* Hrow = J.Hpre + (size_t)ch * J.nbins;
  for (int d = t; d < J.nbins; d += 1024) lb[d] = J.rowstart[d] + (int)Hrow[d];
  __syncthreads();
  for (int e = e0 + t * 4; e < eend; e += 4096) {
    const int4 dv = *(const int4*)(J.dst + e);
    const int4 sv = *(const int4*)(J.src + e);
    const int p0 = atomicAdd(&lb[dv.x], 1); J.csr[p0] = (unsigned short)sv.x;
    const int p1 = atomicAdd(&lb[dv.y], 1); J.csr[p1] = (unsigned short)sv.y;
    const int p2 = atomicAdd(&lb[dv.z], 1); J.csr[p2] = (unsigned short)sv.z;
    const int p3 = atomicAdd(&lb[dv.w], 1); J.csr[p3] = (unsigned short)sv.w;
  }
}

// ---------------- y_r = (h @ W_r) * deg_out^-1/2 — 2-phase dbuf, f32-A + cvt_pk ------
// BK=32 double-buffer (A 2x16KB f32, B 2x8KB bf16 = 48KB). Per step: issue next-tile
// stage (async gload_lds) BEFORE compute, ONE barrier per step (catalog T3-minimum).
// A swizzle: 8 slots, slot^=(row&7); B swizzle: 4 slots, slot^=(row&3); both sides.
struct GemmRel { const float* h; const unsigned short* WT; unsigned short* y;
                 const int* deg_out; int n_src; };
struct GemmParams { GemmRel r[NREL]; };

#define GEMM_JOBS 723

__global__ __launch_bounds__(256) void k_gemm(GemmParams p) {
  if (blockIdx.x >= GEMM_JOBS) {
    const int r = blockIdx.x - GEMM_JOBS;
    if (threadIdx.x < 64)
      ((unsigned*)(p.r[r].y + (size_t)p.r[r].n_src * OUT_F))[threadIdx.x] = 0u;
    return;
  }
  // bijective XCD swizzle: orig -> jobid (m204)
  const int orig = blockIdx.x;
  const int xcd = orig & 7;
  const int i8 = orig >> 3;
  const int q = GEMM_JOBS / 8, rm = GEMM_JOBS % 8;   // 90, 3
  const int g = (xcd < rm ? xcd * (q + 1) : rm * (q + 1) + (xcd - rm) * q) + i8;
  static const int dr[4] = {0, 2, 4, 6};
  static const int pr[3] = {1, 3, 8};
  static const int xr[2] = {5, 9};
  int rel, tile;
  if (g < 252)      { rel = dr[g & 3]; tile = g >> 2; }
  else if (g < 627) { int u = g - 252; rel = pr[u % 3]; tile = u / 3; }
  else if (g < 691) { int u = g - 627; rel = xr[u & 1]; tile = u >> 1; }
  else              { rel = 7; tile = g - 691; }

  const GemmRel R = p.r[rel];
  const int m0 = tile * 128;

  __shared__ float Af[2][128 * 32];            // 2 x 16 KB
  __shared__ unsigned short Bs[2][128 * 32];   // 2 x 8 KB

  const int t = threadIdx.x;
  const int lane = t & 63, wid = t >> 6;
  const int wm = (wid >> 1) * 64, wn = (wid & 1) * 64;
  const int l16 = lane & 15;
  const int x7 = l16 & 7;
  const int x3 = l16 & 3;
  const int fcol = lane >> 4;

  // A staging: 4 issues x 32 rows; wave covers 8 rows (lane>>3), 8 slots (lane&7)
  const int asr = lane >> 3;                       // row-in-group 0..7 (== row&7)
  const int ascol = ((lane & 7) ^ asr) * 4;        // inverse-swizzled f32 col
  const float* ga[4];
#pragma unroll
  for (int i = 0; i < 4; ++i) {
    int grow = m0 + i * 32 + wid * 8 + asr;
    if (grow > R.n_src - 1) grow = R.n_src - 1;    // clamp: finite garbage, not stored
    ga[i] = R.h + (size_t)grow * IN_F + ascol;
  }
  // B staging: 2 issues x 64 rows; wave covers 16 rows (lane>>2), 4 slots (lane&3)
  const int bsr = lane >> 2;                       // 0..15; row&3 == bsr&3
  const int bscol = ((lane & 3) ^ (bsr & 3)) * 8;  // inverse-swizzled bf16 col
  const unsigned short* gb[2];
#pragma unroll
  for (int i = 0; i < 2; ++i) {
    const int lrow = i * 64 + wid * 16 + bsr;
    gb[i] = R.WT + (size_t)lrow * IN_F + bscol;
  }

  f32x4 acc[4][4];
#pragma unroll
  for (int i = 0; i < 4; ++i)
#pragma unroll
    for (int j = 0; j < 4; ++j) acc[i][j] = (f32x4){0.f, 0.f, 0.f, 0.f};

  auto stage = [&](int buf, int k0) {
#pragma unroll
    for (int i = 0; i < 4; ++i)
      gl_lds16(ga[i] + k0, &Af[buf][(i * 32 + wid * 8) * 32]);
#pragma unroll
    for (int i = 0; i < 2; ++i)
      gl_lds16(gb[i] + k0, &Bs[buf][(i * 64 + wid * 16) * 32]);
  };

  stage(0, 0);
  __syncthreads();
  int buf = 0;
#pragma unroll 1
  for (int s = 0; s < 16; ++s) {
    if (s < 15) stage(buf ^ 1, (s + 1) * 32);   // async: hides under compute
    short8 af[4], bf[4];
    const int s0 = fcol * 2;
#pragma unroll
    for (int f = 0; f < 4; ++f) {
      const int Ra = wm + f * 16 + l16;
      const float4 a0 = *(const float4*)&Af[buf][Ra * 32 + ((s0 ^ x7) * 4)];
      const float4 a1 = *(const float4*)&Af[buf][Ra * 32 + (((s0 + 1) ^ x7) * 4)];
      union { unsigned u[4]; short8 s8; } cv;
      asm("v_cvt_pk_bf16_f32 %0, %1, %2" : "=v"(cv.u[0]) : "v"(a0.x), "v"(a0.y));
      asm("v_cvt_pk_bf16_f32 %0, %1, %2" : "=v"(cv.u[1]) : "v"(a0.z), "v"(a0.w));
      asm("v_cvt_pk_bf16_f32 %0, %1, %2" : "=v"(cv.u[2]) : "v"(a1.x), "v"(a1.y));
      asm("v_cvt_pk_bf16_f32 %0, %1, %2" : "=v"(cv.u[3]) : "v"(a1.z), "v"(a1.w));
      af[f] = cv.s8;
      bf[f] = *(const short8*)&Bs[buf][(wn + f * 16 + l16) * 32 + ((fcol ^ x3) * 8)];
    }
#pragma unroll
    for (int i = 0; i < 4; ++i)
#pragma unroll
      for (int j = 0; j < 4; ++j)
        acc[i][j] = __builtin_amdgcn_mfma_f32_16x16x32_bf16(af[i], bf[j], acc[i][j], 0, 0, 0);
    __syncthreads();   // drains vmcnt (next stage done) + lgkm (reads done)
    buf ^= 1;
  }

  const int r4 = (lane >> 4) * 4;  // C/D: col=lane&15, row=(lane>>4)*4+q
#pragma unroll
  for (int i = 0; i < 4; ++i) {
#pragma unroll
    for (int qq = 0; qq < 4; ++qq) {
      const int row = m0 + wm + i * 16 + r4 + qq;
      if (row < R.n_src) {
        const int d = R.deg_out[row];
        const float sc = rsqrtf((float)(d > 1 ? d : 1));
#pragma unroll
        for (int j = 0; j < 4; ++j) {
          const int col = wn + j * 16 + l16;
          R.y[(size_t)row * OUT_F + col] = f2bf(acc[i][j][qq] * sc);
        }
      }
    }
  }
}

// ---------------- gather-aggregate + bias + relu (pad-16, index-prefetch) ------------
struct AggRel { const int* rowstart; const int* deg; const unsigned short* csr;
                const unsigned short* y; const float* b; };
struct AggType { AggRel r[4]; int n_rels; int n_nodes; float* out; };
struct AggParams { AggType t[4]; };

__global__ __launch_bounds__(256) void k_aggregate(AggParams p) {
  const AggType& T = p.t[blockIdx.y];
  const int node = blockIdx.x * 4 + (threadIdx.x >> 6);
  if (node >= T.n_nodes) return;
  const int lane = threadIdx.x & 63;
  const int quarter = lane >> 4;
  const int c8 = (lane & 15) * 8;
  f32x2 ac2[4] = {{0.f,0.f},{0.f,0.f},{0.f,0.f},{0.f,0.f}};
  float bs[8] = {0,0,0,0,0,0,0,0};
#pragma unroll
  for (int rr = 0; rr < 4; ++rr) {
    if (rr < T.n_rels) {
      const AggRel R = T.r[rr];
      const int lo = R.rowstart[node];
      const int hi = R.rowstart[node + 1];   // lo + pad16(deg)
      f32x2 rx2[4] = {{0.f,0.f},{0.f,0.f},{0.f,0.f},{0.f,0.f}};
      int k = lo + quarter;
      if (k < hi) {
        int i0 = R.csr[k], i1 = R.csr[k + 4], i2 = R.csr[k + 8], i3 = R.csr[k + 12];
        for (; k + 16 < hi; k += 16) {   // prefetch next indices, hide csr latency
          const int n0 = R.csr[k + 16], n1 = R.csr[k + 20],
                    n2 = R.csr[k + 24], n3 = R.csr[k + 28];
          const uint4 u0 = *(const uint4*)(R.y + (size_t)i0 * OUT_F + c8);
          const uint4 u1 = *(const uint4*)(R.y + (size_t)i1 * OUT_F + c8);
          const uint4 u2 = *(const uint4*)(R.y + (size_t)i2 * OUT_F + c8);
          const uint4 u3 = *(const uint4*)(R.y + (size_t)i3 * OUT_F + c8);
          acc8(rx2, u0); acc8(rx2, u1); acc8(rx2, u2); acc8(rx2, u3);
          i0 = n0; i1 = n1; i2 = n2; i3 = n3;
        }
        const uint4 u0 = *(const uint4*)(R.y + (size_t)i0 * OUT_F + c8);
        const uint4 u1 = *(const uint4*)(R.y + (size_t)i1 * OUT_F + c8);
        const uint4 u2 = *(const uint4*)(R.y + (size_t)i2 * OUT_F + c8);
        const uint4 u3 = *(const uint4*)(R.y + (size_t)i3 * OUT_F + c8);
        acc8(rx2, u0); acc8(rx2, u1); acc8(rx2, u2); acc8(rx2, u3);
      }
      const int deg = R.deg[node];
      const float s = rsqrtf((float)(deg > 1 ? deg : 1));
      const f32x2 sc2 = {s, s};
#pragma unroll
      for (int qd = 0; qd < 4; ++qd) ac2[qd] += rx2[qd] * sc2;
      const float4 b0 = *(const float4*)(R.b + c8);
      const float4 b1 = *(const float4*)(R.b + c8 + 4);
      bs[0] += b0.x; bs[1] += b0.y; bs[2] += b0.z; bs[3] += b0.w;
      bs[4] += b1.x; bs[5] += b1.y; bs[6] += b1.z; bs[7] += b1.w;
    }
  }
  float ac[8] = {ac2[0].x, ac2[0].y, ac2[1].x, ac2[1].y,
                 ac2[2].x, ac2[2].y, ac2[3].x, ac2[3].y};
#pragma unroll
  for (int qd = 0; qd < 8; ++qd) {
    ac[qd] += __shfl_xor(ac[qd], 16);
    ac[qd] += __shfl_xor(ac[qd], 32);
    ac[qd] += bs[qd];
    ac[qd] = ac[qd] > 0.f ? ac[qd] : 0.f;
  }
  if (quarter == 0) {
    float* dst = T.out + (size_t)node * OUT_F + c8;
    float4 o0 = {ac[0], ac[1], ac[2], ac[3]};
    float4 o1 = {ac[4], ac[5], ac[6], ac[7]};
    *(float4*)dst = o0;
    *(float4*)(dst + 4) = o1;
  }
}

// ---------------- host ----------------
extern "C" void kernel_launch(void* const* d_in, const int* in_sizes, int n_in,
                              void* d_out, int out_size, void* d_ws, size_t ws_size,
                              hipStream_t stream) {
  const float* h[4];
  for (int i = 0; i < 4; ++i) h[i] = (const float*)d_in[i];
  const float* W[NREL]; const float* b[NREL];
  const int* src[NREL]; const int* dst[NREL];
  for (int r = 0; r < NREL; ++r) {
    W[r]   = (const float*)d_in[4 + 2 * r];
    b[r]   = (const float*)d_in[5 + 2 * r];
    src[r] = (const int*)d_in[24 + 2 * r];
    dst[r] = (const int*)d_in[25 + 2 * r];
  }
  float* out = (float*)d_out;

  char* ws = (char*)d_ws;
  size_t off = 0;
  auto alloc = [&](size_t bytes) -> char* {
    char* p = ws + off;
    off = (off + bytes + 255) & ~(size_t)255;
    return p;
  };
  int* degO[NREL];
  { char* base = alloc((size_t)92000 * 4); size_t o = 0;
    for (int r = 0; r < NREL; ++r) { degO[r] = (int*)(base + o); o += (size_t)kNSrc[r] * 4; } }
  int* totI[NREL];
  { char* base = alloc((size_t)92000 * 4); size_t o = 0;
    for (int r = 0; r < NREL; ++r) { totI[r] = (int*)(base + o); o += (size_t)kNDst[r] * 4; } }
  int* rowst[NREL];
  { char* base = alloc((size_t)(92000 + NREL) * 4); size_t o = 0;
    for (int r = 0; r < NREL; ++r) { rowst[r] = (int*)(base + o); o += (size_t)(kNDst[r] + 1) * 4; } }
  unsigned short* csr[NREL];
  { size_t tot = 0; for (int r = 0; r < NREL; ++r) tot += (size_t)kCsrCap[r];
    char* base = alloc(tot * 2); size_t o = 0;
    for (int r = 0; r < NREL; ++r) { csr[r] = (unsigned short*)(base + o); o += (size_t)kCsrCap[r] * 2; } }
  unsigned short* WT[NREL];
  { char* base = alloc((size_t)NREL * IN_F * OUT_F * 2); size_t o = 0;
    for (int r = 0; r < NREL; ++r) { WT[r] = (unsigned short*)(base + o); o += (size_t)IN_F * OUT_F * 2; } }

  // H region and y (+1 dummy row per rel) overlap: H dead after place, y written in gemm.
  size_t hBytes = 0;
  for (int r = 0; r < NREL; ++r) hBytes += (size_t)kNblk8[r] * (kNSrc[r] + kNDst[r]) * 2;
  size_t yBytes = (size_t)(92000 + NREL) * OUT_F * 2;
  char* HY = alloc(hBytes > yBytes ? hBytes : yBytes);
  unsigned short* Hsrc[NREL]; unsigned short* Hdst[NREL];
  { size_t o = 0;
    for (int r = 0; r < NREL; ++r) { Hsrc[r] = (unsigned short*)(HY + o); o += (size_t)kNblk8[r] * kNSrc[r] * 2; }
    for (int r = 0; r < NREL; ++r) { Hdst[r] = (unsigned short*)(HY + o); o += (size_t)kNblk8[r] * kNDst[r] * 2; } }
  unsigned short* y[NREL];
  { size_t o = 0;
    for (int r = 0; r < NREL; ++r) { y[r] = (unsigned short*)(HY + o); o += (size_t)(kNSrc[r] + 1) * OUT_F * 2; } }

  // 1) fused prep: count + W^T
  PrepParams pr;
  for (int r = 0; r < NREL; ++r) {
    pr.cj[r]        = CountJob{src[r], Hsrc[r], kNEdges[r], kNSrc[r]};
    pr.cj[NREL + r] = CountJob{dst[r], Hdst[r], kNEdges[r], kNDst[r]};
  }
  for (int r = 0; r < NREL; ++r) { pr.W[r] = W[r]; pr.WT[r] = WT[r]; }
  k_prep<<<PREP_BLOCKS, 512, 0, stream>>>(pr);

  // 2) column-sum (src) + prefix (dst)
  SBParams sb;
  for (int r = 0; r < NREL; ++r) {
    sb.j[r]        = SBJob{Hsrc[r], degO[r], kNSrc[r], kNblk8[r], 0};
    sb.j[NREL + r] = SBJob{Hdst[r], totI[r], kNDst[r], kNblk8[r], 1};
  }
  k_sumbase<<<dim3((16000 + 255) / 256, 2 * NREL), 256, 0, stream>>>(sb);

  // 3) padded scan (pure)
  ScanParams sp;
  for (int r = 0; r < NREL; ++r) sp.r[r] = ScanRel{totI[r], rowst[r], kNDst[r]};
  k_scan<<<NREL, 512, 0, stream>>>(sp);

  // 4) pad-fill
  PadParams pd;
  for (int r = 0; r < NREL; ++r) pd.j[r] = PadJob{totI[r], rowst[r], csr[r], kNDst[r], kNSrc[r]};
  k_pad<<<dim3((16000 + 255) / 256, NREL), 256, 0, stream>>>(pd);

  // 5) place
  PlaceParams pp;
  for (int r = 0; r < NREL; ++r)
    pp.j[r] = PlaceJob{src[r], dst[r], Hdst[r], rowst[r], csr[r], kNEdges[r], kNDst[r]};
  k_place<<<N_PLC_CH, 1024, 0, stream>>>(pp);

  // 6) GEMM (2-phase dbuf; +10 dummy-row-zero blocks)
  GemmParams gp;
  for (int r = 0; r < NREL; ++r)
    gp.r[r] = GemmRel{h[kRelSrcType[r]], WT[r], y[r], degO[r], kNSrc[r]};
  k_gemm<<<GEMM_JOBS + NREL, 256, 0, stream>>>(gp);

  // 7) aggregate (tail-free, index-prefetch)
  AggParams ap;
  for (int ti = 0; ti < 4; ++ti) {
    AggType& T = ap.t[ti];
    T.n_nodes = kNNodes[ti];
    T.n_rels = kNDstRels[ti];
    T.out = out + kOutOff[ti];
    for (int j = 0; j < 4; ++j) {
      int r = kDstRels[ti][j];
      if (r < 0) r = kDstRels[ti][0];
      T.r[j] = AggRel{rowst[r], totI[r], csr[r], y[r], b[r]};
    }
  }
  k_aggregate<<<dim3((16000 + 3) / 4, 4), 256, 0, stream>>>(ap);
}

// Round 18
// 153.722 us; speedup vs baseline: 1.5099x; 1.1359x over previous
//
#include <hip/hip_runtime.h>
#include <cstddef>
#include <cstdint>

#define IN_F 512
#define OUT_F 128
#define NREL 10
#define MAXBINS 16000

typedef __attribute__((ext_vector_type(8))) short short8;
typedef __attribute__((ext_vector_type(4))) float f32x4;
typedef float f32x2 __attribute__((ext_vector_type(2)));

static const int kNSrc[NREL]   = {8000,16000,8000,16000,8000,4000,8000,4000,16000,4000};
static const int kNDst[NREL]   = {8000,16000,16000,8000,4000,8000,4000,8000,4000,16000};
static const int kNEdges[NREL] = {200000,800000,400000,400000,100000,100000,100000,100000,150000,150000};
static const int kRelSrcType[NREL] = {0,1,0,1,0,2,0,3,1,2};
static const int kNNodes[4] = {8000,16000,4000,4000};
static const size_t kOutOff[4] = {0, 8000ull*OUT_F, 24000ull*OUT_F, 28000ull*OUT_F};
static const size_t kHOff[4] = {0, 8000ull*IN_F, 24000ull*IN_F, 28000ull*IN_F};
static const int kDstRels[4][4] = {{0,3,5,7},{1,2,9,-1},{4,8,-1,-1},{6,-1,-1,-1}};
static const int kNDstRels[4] = {4,3,2,1};
static const int kNblk8[NREL] = {25,98,49,49,13,13,13,13,19,19};   // ceil(E/8192), sum 311
// padded csr capacity per rel: E + 16*n_dst
static const int kCsrCap[NREL] = {328000,1056000,656000,528000,164000,228000,164000,228000,214000,406000};

// count chunks (8192): jobs 0..9 = src, 10..19 = dst
__device__ const int kCntCum[21] = {0,25,123,172,221,234,247,260,273,292,311,
                                    336,434,483,532,545,558,571,584,603,622};
#define N_CNT_CH 622
#define N_WT_CH  80
#define PREP_BLOCKS (N_CNT_CH + N_WT_CH)   // 702
// place chunks (8192)
__device__ const int kPlcCum[11] = {0,25,123,172,221,234,247,260,273,292,311};
#define N_PLC_CH 311
#define PAD_BPR 63                           // pad blocks per relation (63*256 >= 16000)

__device__ __forceinline__ unsigned short f2bf(float f) {
  union { float f; unsigned u; } v; v.f = f;
  unsigned r = v.u + 0x7fffu + ((v.u >> 16) & 1u);
  return (unsigned short)(r >> 16);
}
// unpack uint4 (8 bf16) -> 4 f32 pairs, accumulate
__device__ __forceinline__ void acc8(f32x2* a, uint4 u) {
  union { unsigned v; float f; } lo0, hi0, lo1, hi1, lo2, hi2, lo3, hi3;
  lo0.v = u.x << 16; hi0.v = u.x & 0xffff0000u;
  lo1.v = u.y << 16; hi1.v = u.y & 0xffff0000u;
  lo2.v = u.z << 16; hi2.v = u.z & 0xffff0000u;
  lo3.v = u.w << 16; hi3.v = u.w & 0xffff0000u;
  a[0] += (f32x2){lo0.f, hi0.f};
  a[1] += (f32x2){lo1.f, hi1.f};
  a[2] += (f32x2){lo2.f, hi2.f};
  a[3] += (f32x2){lo3.f, hi3.f};
}
// async global->LDS, 16B/lane (m97 pattern)
__device__ __forceinline__ void gl_lds16(const void* g, const void* l) {
  __builtin_amdgcn_global_load_lds(
      (const __attribute__((address_space(1))) unsigned int*)(g),
      (__attribute__((address_space(3))) unsigned int*)(l), 16, 0, 0);
}

// ---------------- fused prep: count(0..621) | WT(622..701) ---------------------------
struct CountJob { const int* idx; unsigned short* H; int n_edges; int nbins; };
struct PrepParams {
  CountJob cj[2 * NREL];
  const float* W[NREL]; unsigned short* WT[NREL];
};

__global__ __launch_bounds__(512) void k_prep(PrepParams p) {
  __shared__ unsigned lb[MAXBINS / 2];
  const int c = blockIdx.x;
  const int t = threadIdx.x;
  if (c < N_CNT_CH) {
    int j = 0;
    while (c >= kCntCum[j + 1]) ++j;
    const CountJob J = p.cj[j];
    const int ch = c - kCntCum[j];
    const int e0 = ch * 8192;
    const int eend = (e0 + 8192 < J.n_edges) ? e0 + 8192 : J.n_edges;
    const int nw = J.nbins >> 1;
    for (int d = t; d < nw; d += 512) lb[d] = 0;
    __syncthreads();
    for (int e = e0 + t * 4; e < eend; e += 2048) {
      const int4 v = *(const int4*)(J.idx + e);
      atomicAdd(&lb[v.x >> 1], 1u << ((v.x & 1) << 4));
      atomicAdd(&lb[v.y >> 1], 1u << ((v.y & 1) << 4));
      atomicAdd(&lb[v.z >> 1], 1u << ((v.z & 1) << 4));
      atomicAdd(&lb[v.w >> 1], 1u << ((v.w & 1) << 4));
    }
    __syncthreads();
    unsigned short* Hrow = J.H + (size_t)ch * J.nbins;
    for (int d = t; d < nw; d += 512) *(unsigned*)&Hrow[d * 2] = lb[d];
  } else {
    const int u = c - N_CNT_CH;
    const int r = u >> 3;
    const int g0 = (u & 7) * 2048;
    const float* W = p.W[r];
    unsigned short* WT = p.WT[r];
    for (int g = g0 + t; g < g0 + 2048; g += 512) {
      const int k = g >> 5;
      const int n0 = (g & 31) * 4;
      const float4 w = *(const float4*)(W + (size_t)k * OUT_F + n0);
      WT[(size_t)(n0 + 0) * IN_F + k] = f2bf(w.x);
      WT[(size_t)(n0 + 1) * IN_F + k] = f2bf(w.y);
      WT[(size_t)(n0 + 2) * IN_F + k] = f2bf(w.z);
      WT[(size_t)(n0 + 3) * IN_F + k] = f2bf(w.w);
    }
  }
}

// ---------------- fused column-sum (src) + per-bin prefix (dst), unrolled ------------
struct SBJob { unsigned short* H; int* tot; int nbins; int nblocks; int prefix; };
struct SBParams { SBJob j[2 * NREL]; };

__global__ __launch_bounds__(256) void k_sumbase(SBParams p) {
  SBJob J = p.j[blockIdx.y];
  const int bin = blockIdx.x * 256 + threadIdx.x;
  if (bin >= J.nbins) return;
  const int nb = J.nblocks;
  const size_t stride = (size_t)J.nbins;
  unsigned short* H = J.H + bin;
  int run = 0;
  if (J.prefix) {
    int b = 0;
    for (; b + 4 <= nb; b += 4) {       // 4 independent loads in flight
      unsigned short* h0 = H + (size_t)b * stride;
      const int c0 = h0[0];
      const int c1 = h0[stride];
      const int c2 = h0[2 * stride];
      const int c3 = h0[3 * stride];
      h0[0]          = (unsigned short)run;
      h0[stride]     = (unsigned short)(run + c0);
      h0[2 * stride] = (unsigned short)(run + c0 + c1);
      h0[3 * stride] = (unsigned short)(run + c0 + c1 + c2);
      run += c0 + c1 + c2 + c3;
    }
    for (; b < nb; ++b) {
      unsigned short* h0 = H + (size_t)b * stride;
      const int cc = h0[0];
      h0[0] = (unsigned short)run;
      run += cc;
    }
  } else {
    int b = 0;
    int s0 = 0, s1 = 0, s2 = 0, s3 = 0;
    for (; b + 8 <= nb; b += 8) {       // 8 independent loads in flight
      const unsigned short* h0 = H + (size_t)b * stride;
      s0 += h0[0]          + h0[4 * stride];
      s1 += h0[stride]     + h0[5 * stride];
      s2 += h0[2 * stride] + h0[6 * stride];
      s3 += h0[3 * stride] + h0[7 * stride];
    }
    run = s0 + s1 + s2 + s3;
    for (; b < nb; ++b) run += H[(size_t)b * stride];
  }
  J.tot[bin] = run;
}

// ---------------- exclusive scan over PADDED counts (pure scan) ----------------------
struct ScanRel { const int* tot; int* rowstart; int n; };
struct ScanParams { ScanRel r[NREL]; };

__global__ __launch_bounds__(512) void k_scan(ScanParams p) {
  ScanRel R = p.r[blockIdx.x];
  const int t = threadIdx.x;
  const int lane = t & 63, wv = t >> 6;
  const int base = t * 32;
  int v[32];
  int s = 0;
#pragma unroll
  for (int i = 0; i < 32; ++i) {
    int e = base + i;
    int x = (e < R.n) ? R.tot[e] : 0;
    int xp = (x + 15) & ~15;          // pad segment to multiple of 16
    v[i] = s; s += xp;
  }
  int inc = s;
#pragma unroll
  for (int off = 1; off < 64; off <<= 1) {
    int u = __shfl_up(inc, off);
    if (lane >= off) inc += u;
  }
  __shared__ int wsum[8];
  if (lane == 63) wsum[wv] = inc;
  __syncthreads();
  int carry = 0, total = 0;
#pragma unroll
  for (int w = 0; w < 8; ++w) {
    int x = wsum[w];
    if (w < wv) carry += x;
    total += x;
  }
  const int tb = carry + (inc - s);
#pragma unroll
  for (int i = 0; i < 32; ++i) {
    int e = base + i;
    if (e < R.n) R.rowstart[e] = tb + v[i];
  }
  if (t == 0) R.rowstart[R.n] = total;
}

// ---------------- place: 8192-edge chunks, LDS cursors -------------------------------
struct PlaceJob { const int* src; const int* dst; const unsigned short* Hpre; const int* rowstart;
                  unsigned short* csr; int n_edges; int nbins; };
struct PlaceParams { PlaceJob j[NREL]; };

__global__ __launch_bounds__(1024) void k_place(PlaceParams p) {
  __shared__ int lb[MAXBINS];
  const int c = blockIdx.x;
  const int t = threadIdx.x;
  int j = 0;
  while (c >= kPlcCum[j + 1]) ++j;
  const PlaceJob J = p.j[j];
  const int ch = c - kPlcCum[j];
  const int e0 = ch * 8192;
  const int eend = (e0 + 8192 < J.n_edges) ? e0 + 8192 : J.n_edges;
  const unsigned short* Hrow = J.Hpre + (size_t)ch * J.nbins;
  for (int d = t; d < J.nbins; d += 1024) lb[d] = J.rowstart[d] + (int)Hrow[d];
  __syncthreads();
  for (int e = e0 + t * 4; e < eend; e += 4096) {
    const int4 dv = *(const int4*)(J.dst + e);
    const int4 sv = *(const int4*)(J.src + e);
    const int p0 = atomicAdd(&lb[dv.x], 1); J.csr[p0] = (unsigned short)sv.x;
    const int p1 = atomicAdd(&lb[dv.y], 1); J.csr[p1] = (unsigned short)sv.y;
    const int p2 = atomicAdd(&lb[dv.z], 1); J.csr[p2] = (unsigned short)sv.z;
    const int p3 = atomicAdd(&lb[dv.w], 1); J.csr[p3] = (unsigned short)sv.w;
  }
}

// ---------------- GEMM (2-phase dbuf, f32-A + cvt_pk) + fused pad + dummy-zero -------
// grid: [0,723) gemm | [723,733) dummy-row zero | [733,1363) pad-fill blocks.
struct PadJob { const int* tot; const int* rowstart; unsigned short* csr; int nbins; int dummy; };
struct GemmRel { const float* h; const unsigned short* WT; unsigned short* y;
                 const int* deg_out; int n_src; };
struct GemmParams { GemmRel r[NREL]; PadJob pj[NREL]; };

#define GEMM_JOBS 723

__global__ __launch_bounds__(256) void k_gemm(GemmParams p) {
  if (blockIdx.x >= GEMM_JOBS + NREL) {
    // pad-fill: one thread per dst node
    const int u = blockIdx.x - (GEMM_JOBS + NREL);
    const int r = u / PAD_BPR, blk = u % PAD_BPR;
    const PadJob J = p.pj[r];
    const int bin = blk * 256 + threadIdx.x;
    if (bin >= J.nbins) return;
    const int x = J.tot[bin];
    const int xp = (x + 15) & ~15;
    const int lo = J.rowstart[bin];
    const unsigned short d = (unsigned short)J.dummy;
    for (int pk = x; pk < xp; ++pk) J.csr[lo + pk] = d;
    return;
  }
  if (blockIdx.x >= GEMM_JOBS) {
    const int r = blockIdx.x - GEMM_JOBS;
    if (threadIdx.x < 64)
      ((unsigned*)(p.r[r].y + (size_t)p.r[r].n_src * OUT_F))[threadIdx.x] = 0u;
    return;
  }
  // bijective XCD swizzle: orig -> jobid (m204)
  const int orig = blockIdx.x;
  const int xcd = orig & 7;
  const int i8 = orig >> 3;
  const int q = GEMM_JOBS / 8, rm = GEMM_JOBS % 8;   // 90, 3
  const int g = (xcd < rm ? xcd * (q + 1) : rm * (q + 1) + (xcd - rm) * q) + i8;
  static const int dr[4] = {0, 2, 4, 6};
  static const int pr[3] = {1, 3, 8};
  static const int xr[2] = {5, 9};
  int rel, tile;
  if (g < 252)      { rel = dr[g & 3]; tile = g >> 2; }
  else if (g < 627) { int u = g - 252; rel = pr[u % 3]; tile = u / 3; }
  else if (g < 691) { int u = g - 627; rel = xr[u & 1]; tile = u >> 1; }
  else              { rel = 7; tile = g - 691; }

  const GemmRel R = p.r[rel];
  const int m0 = tile * 128;

  __shared__ float Af[2][128 * 32];            // 2 x 16 KB
  __shared__ unsigned short Bs[2][128 * 32];   // 2 x 8 KB

  const int t = threadIdx.x;
  const int lane = t & 63, wid = t >> 6;
  const int wm = (wid >> 1) * 64, wn = (wid & 1) * 64;
  const int l16 = lane & 15;
  const int x7 = l16 & 7;
  const int x3 = l16 & 3;
  const int fcol = lane >> 4;

  // A staging: 4 issues x 32 rows; wave covers 8 rows (lane>>3), 8 slots (lane&7)
  const int asr = lane >> 3;
  const int ascol = ((lane & 7) ^ asr) * 4;
  const float* ga[4];
#pragma unroll
  for (int i = 0; i < 4; ++i) {
    int grow = m0 + i * 32 + wid * 8 + asr;
    if (grow > R.n_src - 1) grow = R.n_src - 1;
    ga[i] = R.h + (size_t)grow * IN_F + ascol;
  }
  // B staging: 2 issues x 64 rows; wave covers 16 rows (lane>>2), 4 slots (lane&3)
  const int bsr = lane >> 2;
  const int bscol = ((lane & 3) ^ (bsr & 3)) * 8;
  const unsigned short* gb[2];
#pragma unroll
  for (int i = 0; i < 2; ++i) {
    const int lrow = i * 64 + wid * 16 + bsr;
    gb[i] = R.WT + (size_t)lrow * IN_F + bscol;
  }

  f32x4 acc[4][4];
#pragma unroll
  for (int i = 0; i < 4; ++i)
#pragma unroll
    for (int j = 0; j < 4; ++j) acc[i][j] = (f32x4){0.f, 0.f, 0.f, 0.f};

  auto stage = [&](int buf, int k0) {
#pragma unroll
    for (int i = 0; i < 4; ++i)
      gl_lds16(ga[i] + k0, &Af[buf][(i * 32 + wid * 8) * 32]);
#pragma unroll
    for (int i = 0; i < 2; ++i)
      gl_lds16(gb[i] + k0, &Bs[buf][(i * 64 + wid * 16) * 32]);
  };

  stage(0, 0);
  __syncthreads();
  int buf = 0;
#pragma unroll 1
  for (int s = 0; s < 16; ++s) {
    if (s < 15) stage(buf ^ 1, (s + 1) * 32);   // async: hides under compute
    short8 af[4], bf[4];
    const int s0 = fcol * 2;
#pragma unroll
    for (int f = 0; f < 4; ++f) {
      const int Ra = wm + f * 16 + l16;
      const float4 a0 = *(const float4*)&Af[buf][Ra * 32 + ((s0 ^ x7) * 4)];
      const float4 a1 = *(const float4*)&Af[buf][Ra * 32 + (((s0 + 1) ^ x7) * 4)];
      union { unsigned u[4]; short8 s8; } cv;
      asm("v_cvt_pk_bf16_f32 %0, %1, %2" : "=v"(cv.u[0]) : "v"(a0.x), "v"(a0.y));
      asm("v_cvt_pk_bf16_f32 %0, %1, %2" : "=v"(cv.u[1]) : "v"(a0.z), "v"(a0.w));
      asm("v_cvt_pk_bf16_f32 %0, %1, %2" : "=v"(cv.u[2]) : "v"(a1.x), "v"(a1.y));
      asm("v_cvt_pk_bf16_f32 %0, %1, %2" : "=v"(cv.u[3]) : "v"(a1.z), "v"(a1.w));
      af[f] = cv.s8;
      bf[f] = *(const short8*)&Bs[buf][(wn + f * 16 + l16) * 32 + ((fcol ^ x3) * 8)];
    }
#pragma unroll
    for (int i = 0; i < 4; ++i)
#pragma unroll
      for (int j = 0; j < 4; ++j)
        acc[i][j] = __builtin_amdgcn_mfma_f32_16x16x32_bf16(af[i], bf[j], acc[i][j], 0, 0, 0);
    __syncthreads();   // drains vmcnt (next stage done) + lgkm (reads done)
    buf ^= 1;
  }

  const int r4 = (lane >> 4) * 4;  // C/D: col=lane&15, row=(lane>>4)*4+q
#pragma unroll
  for (int i = 0; i < 4; ++i) {
#pragma unroll
    for (int qq = 0; qq < 4; ++qq) {
      const int row = m0 + wm + i * 16 + r4 + qq;
      if (row < R.n_src) {
        const int d = R.deg_out[row];
        const float sc = rsqrtf((float)(d > 1 ? d : 1));
#pragma unroll
        for (int j = 0; j < 4; ++j) {
          const int col = wn + j * 16 + l16;
          R.y[(size_t)row * OUT_F + col] = f2bf(acc[i][j][qq] * sc);
        }
      }
    }
  }
}

// ---------------- gather-aggregate + bias + relu (pad-16, index-prefetch) ------------
struct AggRel { const int* rowstart; const int* deg; const unsigned short* csr;
                const unsigned short* y; const float* b; };
struct AggType { AggRel r[4]; int n_rels; int n_nodes; float* out; };
struct AggParams { AggType t[4]; };

__global__ __launch_bounds__(256) void k_aggregate(AggParams p) {
  const AggType& T = p.t[blockIdx.y];
  const int node = blockIdx.x * 4 + (threadIdx.x >> 6);
  if (node >= T.n_nodes) return;
  const int lane = threadIdx.x & 63;
  const int quarter = lane >> 4;
  const int c8 = (lane & 15) * 8;
  f32x2 ac2[4] = {{0.f,0.f},{0.f,0.f},{0.f,0.f},{0.f,0.f}};
  float bs[8] = {0,0,0,0,0,0,0,0};
#pragma unroll
  for (int rr = 0; rr < 4; ++rr) {
    if (rr < T.n_rels) {
      const AggRel R = T.r[rr];
      const int lo = R.rowstart[node];
      const int hi = R.rowstart[node + 1];   // lo + pad16(deg)
      f32x2 rx2[4] = {{0.f,0.f},{0.f,0.f},{0.f,0.f},{0.f,0.f}};
      int k = lo + quarter;
      if (k < hi) {
        int i0 = R.csr[k], i1 = R.csr[k + 4], i2 = R.csr[k + 8], i3 = R.csr[k + 12];
        for (; k + 16 < hi; k += 16) {   // prefetch next indices, hide csr latency
          const int n0 = R.csr[k + 16], n1 = R.csr[k + 20],
                    n2 = R.csr[k + 24], n3 = R.csr[k + 28];
          const uint4 u0 = *(const uint4*)(R.y + (size_t)i0 * OUT_F + c8);
          const uint4 u1 = *(const uint4*)(R.y + (size_t)i1 * OUT_F + c8);
          const uint4 u2 = *(const uint4*)(R.y + (size_t)i2 * OUT_F + c8);
          const uint4 u3 = *(const uint4*)(R.y + (size_t)i3 * OUT_F + c8);
          acc8(rx2, u0); acc8(rx2, u1); acc8(rx2, u2); acc8(rx2, u3);
          i0 = n0; i1 = n1; i2 = n2; i3 = n3;
        }
        const uint4 u0 = *(const uint4*)(R.y + (size_t)i0 * OUT_F + c8);
        const uint4 u1 = *(const uint4*)(R.y + (size_t)i1 * OUT_F + c8);
        const uint4 u2 = *(const uint4*)(R.y + (size_t)i2 * OUT_F + c8);
        const uint4 u3 = *(const uint4*)(R.y + (size_t)i3 * OUT_F + c8);
        acc8(rx2, u0); acc8(rx2, u1); acc8(rx2, u2); acc8(rx2, u3);
      }
      const int deg = R.deg[node];
      const float s = rsqrtf((float)(deg > 1 ? deg : 1));
      const f32x2 sc2 = {s, s};
#pragma unroll
      for (int qd = 0; qd < 4; ++qd) ac2[qd] += rx2[qd] * sc2;
      const float4 b0 = *(const float4*)(R.b + c8);
      const float4 b1 = *(const float4*)(R.b + c8 + 4);
      bs[0] += b0.x; bs[1] += b0.y; bs[2] += b0.z; bs[3] += b0.w;
      bs[4] += b1.x; bs[5] += b1.y; bs[6] += b1.z; bs[7] += b1.w;
    }
  }
  float ac[8] = {ac2[0].x, ac2[0].y, ac2[1].x, ac2[1].y,
                 ac2[2].x, ac2[2].y, ac2[3].x, ac2[3].y};
#pragma unroll
  for (int qd = 0; qd < 8; ++qd) {
    ac[qd] += __shfl_xor(ac[qd], 16);
    ac[qd] += __shfl_xor(ac[qd], 32);
    ac[qd] += bs[qd];
    ac[qd] = ac[qd] > 0.f ? ac[qd] : 0.f;
  }
  if (quarter == 0) {
    float* dst = T.out + (size_t)node * OUT_F + c8;
    float4 o0 = {ac[0], ac[1], ac[2], ac[3]};
    float4 o1 = {ac[4], ac[5], ac[6], ac[7]};
    *(float4*)dst = o0;
    *(float4*)(dst + 4) = o1;
  }
}

// ---------------- host ----------------
extern "C" void kernel_launch(void* const* d_in, const int* in_sizes, int n_in,
                              void* d_out, int out_size, void* d_ws, size_t ws_size,
                              hipStream_t stream) {
  const float* h[4];
  for (int i = 0; i < 4; ++i) h[i] = (const float*)d_in[i];
  const float* W[NREL]; const float* b[NREL];
  const int* src[NREL]; const int* dst[NREL];
  for (int r = 0; r < NREL; ++r) {
    W[r]   = (const float*)d_in[4 + 2 * r];
    b[r]   = (const float*)d_in[5 + 2 * r];
    src[r] = (const int*)d_in[24 + 2 * r];
    dst[r] = (const int*)d_in[25 + 2 * r];
  }
  float* out = (float*)d_out;

  char* ws = (char*)d_ws;
  size_t off = 0;
  auto alloc = [&](size_t bytes) -> char* {
    char* p = ws + off;
    off = (off + bytes + 255) & ~(size_t)255;
    return p;
  };
  int* degO[NREL];
  { char* base = alloc((size_t)92000 * 4); size_t o = 0;
    for (int r = 0; r < NREL; ++r) { degO[r] = (int*)(base + o); o += (size_t)kNSrc[r] * 4; } }
  int* totI[NREL];
  { char* base = alloc((size_t)92000 * 4); size_t o = 0;
    for (int r = 0; r < NREL; ++r) { totI[r] = (int*)(base + o); o += (size_t)kNDst[r] * 4; } }
  int* rowst[NREL];
  { char* base = alloc((size_t)(92000 + NREL) * 4); size_t o = 0;
    for (int r = 0; r < NREL; ++r) { rowst[r] = (int*)(base + o); o += (size_t)(kNDst[r] + 1) * 4; } }
  unsigned short* csr[NREL];
  { size_t tot = 0; for (int r = 0; r < NREL; ++r) tot += (size_t)kCsrCap[r];
    char* base = alloc(tot * 2); size_t o = 0;
    for (int r = 0; r < NREL; ++r) { csr[r] = (unsigned short*)(base + o); o += (size_t)kCsrCap[r] * 2; } }
  unsigned short* WT[NREL];
  { char* base = alloc((size_t)NREL * IN_F * OUT_F * 2); size_t o = 0;
    for (int r = 0; r < NREL; ++r) { WT[r] = (unsigned short*)(base + o); o += (size_t)IN_F * OUT_F * 2; } }

  // H region and y (+1 dummy row per rel) overlap: H dead after place, y written in gemm.
  size_t hBytes = 0;
  for (int r = 0; r < NREL; ++r) hBytes += (size_t)kNblk8[r] * (kNSrc[r] + kNDst[r]) * 2;
  size_t yBytes = (size_t)(92000 + NREL) * OUT_F * 2;
  char* HY = alloc(hBytes > yBytes ? hBytes : yBytes);
  unsigned short* Hsrc[NREL]; unsigned short* Hdst[NREL];
  { size_t o = 0;
    for (int r = 0; r < NREL; ++r) { Hsrc[r] = (unsigned short*)(HY + o); o += (size_t)kNblk8[r] * kNSrc[r] * 2; }
    for (int r = 0; r < NREL; ++r) { Hdst[r] = (unsigned short*)(HY + o); o += (size_t)kNblk8[r] * kNDst[r] * 2; } }
  unsigned short* y[NREL];
  { size_t o = 0;
    for (int r = 0; r < NREL; ++r) { y[r] = (unsigned short*)(HY + o); o += (size_t)(kNSrc[r] + 1) * OUT_F * 2; } }

  // 1) fused prep: count + W^T
  PrepParams pr;
  for (int r = 0; r < NREL; ++r) {
    pr.cj[r]        = CountJob{src[r], Hsrc[r], kNEdges[r], kNSrc[r]};
    pr.cj[NREL + r] = CountJob{dst[r], Hdst[r], kNEdges[r], kNDst[r]};
  }
  for (int r = 0; r < NREL; ++r) { pr.W[r] = W[r]; pr.WT[r] = WT[r]; }
  k_prep<<<PREP_BLOCKS, 512, 0, stream>>>(pr);

  // 2) column-sum (src) + prefix (dst), latency-unrolled
  SBParams sb;
  for (int r = 0; r < NREL; ++r) {
    sb.j[r]        = SBJob{Hsrc[r], degO[r], kNSrc[r], kNblk8[r], 0};
    sb.j[NREL + r] = SBJob{Hdst[r], totI[r], kNDst[r], kNblk8[r], 1};
  }
  k_sumbase<<<dim3((16000 + 255) / 256, 2 * NREL), 256, 0, stream>>>(sb);

  // 3) padded scan (pure)
  ScanParams sp;
  for (int r = 0; r < NREL; ++r) sp.r[r] = ScanRel{totI[r], rowst[r], kNDst[r]};
  k_scan<<<NREL, 512, 0, stream>>>(sp);

  // 4) place
  PlaceParams pp;
  for (int r = 0; r < NREL; ++r)
    pp.j[r] = PlaceJob{src[r], dst[r], Hdst[r], rowst[r], csr[r], kNEdges[r], kNDst[r]};
  k_place<<<N_PLC_CH, 1024, 0, stream>>>(pp);

  // 5) GEMM + fused pad-fill + dummy-row zero
  GemmParams gp;
  for (int r = 0; r < NREL; ++r) {
    gp.r[r] = GemmRel{h[kRelSrcType[r]], WT[r], y[r], degO[r], kNSrc[r]};
    gp.pj[r] = PadJob{totI[r], rowst[r], csr[r], kNDst[r], kNSrc[r]};
  }
  k_gemm<<<GEMM_JOBS + NREL + PAD_BPR * NREL, 256, 0, stream>>>(gp);

  // 6) aggregate (tail-free, index-prefetch)
  AggParams ap;
  for (int ti = 0; ti < 4; ++ti) {
    AggType& T = ap.t[ti];
    T.n_nodes = kNNodes[ti];
    T.n_rels = kNDstRels[ti];
    T.out = out + kOutOff[ti];
    for (int j = 0; j < 4; ++j) {
      int r = kDstRels[ti][j];
      if (r < 0) r = kDstRels[ti][0];
      T.r[j] = AggRel{rowst[r], totI[r], csr[r], y[r], b[r]};
    }
  }
  k_aggregate<<<dim3((16000 + 3) / 4, 4), 256, 0, stream>>>(ap);
}